// Round 1
// baseline (285.011 us; speedup 1.0000x reference)
//
#include <hip/hip_runtime.h>
#include <hip/hip_bf16.h>
#include <stdint.h>

#define B_ 64
#define N_ 1024
#define E_ 16384
#define F_ 128
#define H_ 64
#define T_ 10
#define BN (B_*N_)   // 65536
#define BE (B_*E_)   // 1048576

// sigmoid(z) >= p  <=>  z >= log(p/(1-p))
#define TH_INNER (-0.84729786f)   // logit(0.3)
#define TH_CROSS (-2.1972246f)    // logit(0.1)

typedef __attribute__((ext_vector_type(8))) short short8;  // bf16x8 MFMA frag
typedef __attribute__((ext_vector_type(4))) float f32x4;   // MFMA acc

__device__ __forceinline__ float ld1(const void* p, int i, int bf) {
    if (bf) {
        uint16_t u = ((const uint16_t*)p)[i];
        return __uint_as_float(((uint32_t)u) << 16);
    }
    return ((const float*)p)[i];
}

__device__ __forceinline__ short to_bf(float x) {
    return (short)__bfloat16_as_ushort(__float2bfloat16(x));
}

__device__ __forceinline__ uint32_t pack_bf2(float lo, float hi) {
    uint32_t l = (uint32_t)__bfloat16_as_ushort(__float2bfloat16(lo));
    uint32_t h = (uint32_t)__bfloat16_as_ushort(__float2bfloat16(hi));
    return l | (h << 16);
}

__device__ __forceinline__ float bflo(uint32_t u) { return __uint_as_float(u << 16); }
__device__ __forceinline__ float bfhi(uint32_t u) { return __uint_as_float(u & 0xffff0000u); }

// ---------------- block-per-graph: count -> wave scan -> dense CSR scatter ----------------
__global__ __launch_bounds__(1024) void k_bucket(const int* __restrict__ src,
                                                 const int* __restrict__ dst,
                                                 int* __restrict__ cnt,
                                                 int* __restrict__ offs,
                                                 int* __restrict__ bucket,
                                                 float* __restrict__ gsum,
                                                 uint32_t* __restrict__ y1pad,
                                                 uint32_t* __restrict__ y2pad) {
    __shared__ int lcnt[N_];
    __shared__ int wsum[16];
    int g = blockIdx.x, t = threadIdx.x;
    lcnt[t] = 0;
    if (t < 64) gsum[g * 64 + t] = 0.f;           // zero this graph's pool row
    if (g == 0) {                                 // zero pad rows once
        if (t < 32) y1pad[t] = 0;
        else if (t < 64) y2pad[t - 32] = 0;
    }
    __syncthreads();
#pragma unroll
    for (int it = 0; it < 16; ++it) {
        int i = g * E_ + it * 1024 + t;
        atomicAdd(&lcnt[dst[i]], 1);
    }
    __syncthreads();
    int v = lcnt[t];
    int sc = v;                                    // wave-level inclusive scan
#pragma unroll
    for (int d = 1; d < 64; d <<= 1) {
        int u = __shfl_up(sc, d);
        if ((t & 63) >= d) sc += u;
    }
    if ((t & 63) == 63) wsum[t >> 6] = sc;
    __syncthreads();
    if (t < 16) {                                  // scan the 16 wave sums
        int wsc = wsum[t];
#pragma unroll
        for (int d = 1; d < 16; d <<= 1) {
            int u = __shfl_up(wsc, d);
            if (t >= d) wsc += u;
        }
        wsum[t] = wsc;
    }
    __syncthreads();
    int base = sc - v + ((t >= 64) ? wsum[(t >> 6) - 1] : 0);  // exclusive prefix
    cnt[g * N_ + t] = v;
    offs[g * N_ + t] = g * E_ + base;             // absolute offset into bucket
    lcnt[t] = base;                               // reuse as within-graph cursor
    __syncthreads();
#pragma unroll
    for (int it = 0; it < 16; ++it) {
        int i = g * E_ + it * 1024 + t;
        int d = dst[i];
        int p = atomicAdd(&lcnt[d], 1);
        bucket[(size_t)g * E_ + p] = g * N_ + src[i];
    }
}

// ---------------- B fragments (W1|tokens^T and W2) + publish dtype flag ----------------
__global__ __launch_bounds__(256) void k_prep(const void* __restrict__ W1,
                                              const void* __restrict__ W2,
                                              const void* __restrict__ tokens,
                                              int* __restrict__ flag,
                                              short8* __restrict__ Bfr,
                                              short8* __restrict__ Bfr2) {
    uint32_t du = ((const uint32_t*)tokens)[threadIdx.x & 63];
    float dlo = __uint_as_float(du << 16);
    unsigned long long vote = __ballot(fabsf(dlo) <= 1.0f);
    int bf = (vote == ~0ull) ? 1 : 0;
    if (blockIdx.x == 0 && threadIdx.x == 0) *flag = bf;

    int f = blockIdx.x * 256 + threadIdx.x;      // [0, 1792)
    if (f < 1280) {                              // Bfr: [128 x 80] = W1 | tokens^T
        int c = f / 320, rem = f % 320;
        int nt = rem / 64, lane = rem % 64;
        int q = lane >> 4, n = nt * 16 + (lane & 15);
        int k0 = c * 32 + q * 8;
        short8 v;
#pragma unroll
        for (int j = 0; j < 8; ++j) {
            int k = k0 + j;
            float x = 0.f;
            if (n < H_) x = ld1(W1, k * H_ + n, bf);
            else if (n < H_ + T_) x = ld1(tokens, (n - H_) * F_ + k, bf);
            v[j] = to_bf(x);
        }
        Bfr[f] = v;
    } else {                                     // Bfr2: W2 [64 x 64]
        int f2 = f - 1280;
        int c = f2 / 256, rem = f2 % 256;
        int nt = rem / 64, lane = rem % 64;
        int q = lane >> 4, n = nt * 16 + (lane & 15);
        int k0 = c * 32 + q * 8;
        short8 v;
#pragma unroll
        for (int j = 0; j < 8; ++j) v[j] = to_bf(ld1(W2, (k0 + j) * H_ + n, bf));
        Bfr2[f2] = v;
    }
}

// ---------------- token stream via MFMA (1 wave); writes P rows into y1/y2 ----------------
__global__ __launch_bounds__(64) void k_tok(const void* __restrict__ tokens,
                                            const void* __restrict__ b1,
                                            const void* __restrict__ b2,
                                            const short8* __restrict__ Bfr,
                                            const short8* __restrict__ Bfr2,
                                            const int* __restrict__ flag,
                                            uint32_t* __restrict__ y1,
                                            uint32_t* __restrict__ y2,
                                            float* __restrict__ tok_sum) {
    __shared__ float nm[T_ * 16];
    __shared__ float ist_s[16], idt_s[16];
    __shared__ float htbuf[T_ * 64];
    __shared__ float h1s[T_ * 64];
    int bf = *flag;
    int l = threadIdx.x;
    int m = l & 15, q = l >> 4;
    int mrow = (m < T_) ? m : (T_ - 1);
    short8 afr[4];
    if (bf) {
        const short8* ar = (const short8*)((const uint16_t*)tokens + mrow * F_);
#pragma unroll
        for (int c = 0; c < 4; ++c) afr[c] = ar[c * 4 + q];
    } else {
        const float* ar = (const float*)tokens + mrow * F_;
#pragma unroll
        for (int c = 0; c < 4; ++c)
#pragma unroll
            for (int j = 0; j < 8; ++j) afr[c][j] = to_bf(ar[c * 32 + q * 8 + j]);
    }
    f32x4 accM = {};
    f32x4 acc1[4] = {};
#pragma unroll
    for (int c = 0; c < 4; ++c) {
        accM = __builtin_amdgcn_mfma_f32_16x16x32_bf16(afr[c], Bfr[(c * 5 + 4) * 64 + l], accM, 0, 0, 0);
#pragma unroll
        for (int nt = 0; nt < 4; ++nt)
            acc1[nt] = __builtin_amdgcn_mfma_f32_16x16x32_bf16(afr[c], Bfr[(c * 5 + nt) * 64 + l], acc1[nt], 0, 0, 0);
    }
    int cnt = 0;
#pragma unroll
    for (int r = 0; r < 4; ++r) {
        int row = q * 4 + r;
        if (row < T_ && m < T_ && accM[r] >= TH_INNER) cnt++;
    }
    cnt += __shfl_xor(cnt, 16);
    cnt += __shfl_xor(cnt, 32);
    float deg = 1.f + (float)cnt;
    float istc = 1.f / sqrtf(deg);
    float idtc = 1.f / deg;
    if (q == 0 && m < T_) { ist_s[m] = istc; idt_s[m] = idtc; }
#pragma unroll
    for (int nt = 0; nt < 4; ++nt)
#pragma unroll
        for (int r = 0; r < 4; ++r) {
            int row = q * 4 + r;
            if (row < T_) htbuf[row * 64 + nt * 16 + m] = acc1[nt][r];
        }
    __syncthreads();
    if (m < T_) {
#pragma unroll
        for (int r = 0; r < 4; ++r) {
            int row = q * 4 + r;
            if (row < T_)
                nm[row * 16 + m] = (accM[r] >= TH_INNER) ? ist_s[row] * istc : 0.f;
        }
    }
    __syncthreads();
    float htc[T_];
#pragma unroll
    for (int s = 0; s < T_; ++s) htc[s] = htbuf[s * 64 + l];
    float b1f = ld1(b1, l, bf);
#pragma unroll
    for (int t = 0; t < T_; ++t) {
        float a = htc[t] * idt_s[t] + b1f;
#pragma unroll
        for (int s = 0; s < T_; ++s) a += nm[t * 16 + s] * htc[s];
        a = (a >= 0.f) ? a : 0.01f * a;
        h1s[t * 64 + l] = a;
        float v = ist_s[t] * htc[t];              // P1 row -> y1[BN+1+t]
        float vh = __shfl(v, l + 1);
        if ((l & 1) == 0) y1[(size_t)(BN + 1 + t) * 32 + (l >> 1)] = pack_bf2(v, vh);
    }
    __syncthreads();
    short8 a2fr[2];
#pragma unroll
    for (int c = 0; c < 2; ++c)
#pragma unroll
        for (int j = 0; j < 8; ++j) a2fr[c][j] = to_bf(h1s[mrow * 64 + c * 32 + q * 8 + j]);
    f32x4 acc2[4] = {};
#pragma unroll
    for (int nt = 0; nt < 4; ++nt)
#pragma unroll
        for (int c = 0; c < 2; ++c)
            acc2[nt] = __builtin_amdgcn_mfma_f32_16x16x32_bf16(a2fr[c], Bfr2[(c * 4 + nt) * 64 + l], acc2[nt], 0, 0, 0);
#pragma unroll
    for (int nt = 0; nt < 4; ++nt)
#pragma unroll
        for (int r = 0; r < 4; ++r) {
            int row = q * 4 + r;
            if (row < T_) htbuf[row * 64 + nt * 16 + m] = acc2[nt][r];
        }
    __syncthreads();
    float b2f = ld1(b2, l, bf);
#pragma unroll
    for (int s = 0; s < T_; ++s) htc[s] = htbuf[s * 64 + l];
    float ts = 0.f;
#pragma unroll
    for (int t = 0; t < T_; ++t) {
        float o = htc[t] * idt_s[t] + b2f;
#pragma unroll
        for (int s = 0; s < T_; ++s) o += nm[t * 16 + s] * htc[s];
        ts += o;
        float v = ist_s[t] * htc[t];              // P2 row -> y2[BN+1+t]
        float vh = __shfl(v, l + 1);
        if ((l & 1) == 0) y2[(size_t)(BN + 1 + t) * 32 + (l >> 1)] = pack_bf2(v, vh);
    }
    tok_sum[l] = ts;
}

// ---------------- node GEMM: y1 + token-mask store + inv_s (no CSR appends) ----------------
__global__ __launch_bounds__(256) void k_node_mfma(const void* __restrict__ x,
                                                   const short8* __restrict__ Bfr,
                                                   const int* __restrict__ cnt,
                                                   const int* __restrict__ flag,
                                                   uint32_t* __restrict__ y1,
                                                   float* __restrict__ inv_s,
                                                   int* __restrict__ maskA) {
    int bf = *flag;
    int tid = threadIdx.x;
    int lane = tid & 63, wv = tid >> 6;
    int g = blockIdx.x & 63, c = blockIdx.x >> 6;   // XCD swizzle
    int row0 = g * N_ + c * 64 + wv * 16;
    int m = lane & 15, q = lane >> 4;
    int row = row0 + m;
    short8 afr[4];
    if (bf) {
        const short8* ar = (const short8*)((const uint16_t*)x + (size_t)row * F_);
#pragma unroll
        for (int cc = 0; cc < 4; ++cc) afr[cc] = ar[cc * 4 + q];
    } else {
        const float* ar = (const float*)x + (size_t)row * F_;
#pragma unroll
        for (int cc = 0; cc < 4; ++cc)
#pragma unroll
            for (int j = 0; j < 8; ++j)
                afr[cc][j] = to_bf(ar[cc * 32 + q * 8 + j]);
    }
    f32x4 acc[5] = {};
#pragma unroll
    for (int nt = 0; nt < 5; ++nt)
#pragma unroll
        for (int cc = 0; cc < 4; ++cc) {
            short8 bfr = Bfr[(cc * 5 + nt) * 64 + lane];
            acc[nt] = __builtin_amdgcn_mfma_f32_16x16x32_bf16(afr[cc], bfr, acc[nt], 0, 0, 0);
        }
    unsigned long long bal[4];
#pragma unroll
    for (int r = 0; r < 4; ++r) {
        int pred = (m < T_) && (acc[4][r] >= TH_CROSS);
        bal[r] = __ballot(pred);
    }
    float isv[4];
#pragma unroll
    for (int r = 0; r < 4; ++r) {
        int node = row0 + q * 4 + r;
        int mk = (int)((bal[r] >> (q * 16)) & 0x3FF);
        int ec = cnt[node];
        int pc = __popc((unsigned)mk);
        float deg = 1.f + (float)ec + (float)pc;
        isv[r] = 1.f / sqrtf(deg);
        if (m == 0) { inv_s[node] = isv[r]; maskA[node] = mk; }
    }
#pragma unroll
    for (int r = 0; r < 4; ++r) {
        int node = row0 + q * 4 + r;
#pragma unroll
        for (int nt = 0; nt < 4; ++nt) {
            float v = acc[nt][r] * isv[r];
            float vh = __shfl(v, lane + 1);
            if ((m & 1) == 0)
                y1[(size_t)node * 32 + nt * 8 + (m >> 1)] = pack_bf2(v, vh);
        }
    }
}

// ---------------- dwordx4 gather: 8 rows/instr, mask-expanded virtual edges,
// ---------------- reduce-scatter butterfly -> one output column per lane ----------------
__device__ __forceinline__ float gather8(const uint32_t* __restrict__ yu,
                                         const int* __restrict__ brow,
                                         int idx_cur, int cnt, int msk, int node,
                                         int lane, int r8, int wp) {
    float a0 = 0.f, a1 = 0.f, a2 = 0.f, a3 = 0.f;
    float a4 = 0.f, a5 = 0.f, a6 = 0.f, a7 = 0.f;
    auto grp = [&](int half, int cbat) {
        int s[4];
#pragma unroll
        for (int j = 0; j < 4; ++j) {
            int e = half + 8 * j + r8;
            int sv = __shfl(idx_cur, e & 63);
            s[j] = (e < cbat) ? sv : BN;          // BN = zero row
        }
        uint4 u[4];
#pragma unroll
        for (int j = 0; j < 4; ++j)
            u[j] = ((const uint4*)(yu + (size_t)s[j] * 32))[wp];
#pragma unroll
        for (int j = 0; j < 4; ++j) {
            a0 += bflo(u[j].x); a1 += bfhi(u[j].x);
            a2 += bflo(u[j].y); a3 += bfhi(u[j].y);
            a4 += bflo(u[j].z); a5 += bfhi(u[j].z);
            a6 += bflo(u[j].w); a7 += bfhi(u[j].w);
        }
    };
    int eb = 0;
    while (true) {
        int cbat = min(cnt - eb, 64);
        if (cbat > 0) grp(0, cbat);
        if (cbat > 32) grp(32, cbat);
        eb += 64;
        if (eb >= cnt) break;
        idx_cur = brow[eb + lane];               // rare (cnt > 64)
    }
    {   // virtual edges: tokens by mask (rows BN+1+t) + self loop (row node)
        int v1 = 8 + r8;
        int s0 = ((msk >> r8) & 1) ? (BN + 1 + r8) : BN;
        int s1 = (v1 < T_) ? (((msk >> v1) & 1) ? (BN + 1 + v1) : BN)
                           : ((v1 == T_) ? node : BN);
        uint4 u0 = ((const uint4*)(yu + (size_t)s0 * 32))[wp];
        uint4 u1 = ((const uint4*)(yu + (size_t)s1 * 32))[wp];
        a0 += bflo(u0.x) + bflo(u1.x); a1 += bfhi(u0.x) + bfhi(u1.x);
        a2 += bflo(u0.y) + bflo(u1.y); a3 += bfhi(u0.y) + bfhi(u1.y);
        a4 += bflo(u0.z) + bflo(u1.z); a5 += bfhi(u0.z) + bfhi(u1.z);
        a6 += bflo(u0.w) + bflo(u1.w); a7 += bfhi(u0.w) + bfhi(u1.w);
    }
    // reduce-scatter over row-lane groups (xor 8,16,32): lane ends with col
    // col = 8*wp + 4*b3 + 2*b4 + b5
    bool h8 = (lane & 8) != 0;
    float k0 = h8 ? a4 : a0, s0v = h8 ? a0 : a4;
    float k1 = h8 ? a5 : a1, s1v = h8 ? a1 : a5;
    float k2 = h8 ? a6 : a2, s2v = h8 ? a2 : a6;
    float k3 = h8 ? a7 : a3, s3v = h8 ? a3 : a7;
    k0 += __shfl_xor(s0v, 8);
    k1 += __shfl_xor(s1v, 8);
    k2 += __shfl_xor(s2v, 8);
    k3 += __shfl_xor(s3v, 8);
    bool h16 = (lane & 16) != 0;
    float m0 = h16 ? k2 : k0, n0 = h16 ? k0 : k2;
    float m1 = h16 ? k3 : k1, n1 = h16 ? k1 : k3;
    m0 += __shfl_xor(n0, 16);
    m1 += __shfl_xor(n1, 16);
    bool h32 = (lane & 32) != 0;
    float r0 = h32 ? m1 : m0, rs = h32 ? m0 : m1;
    r0 += __shfl_xor(rs, 32);
    return r0;
}

// ---------------- layer1: 8 nodes/wave gather + epilogue + fused h1@W2 -> y2 ----------------
__global__ __launch_bounds__(256, 8) void k_layer1(const uint32_t* __restrict__ y1,
                                                   const float* __restrict__ inv_s,
                                                   const int* __restrict__ cnt,
                                                   const int* __restrict__ offs,
                                                   const int* __restrict__ maskA,
                                                   const int* __restrict__ bucket,
                                                   const void* __restrict__ b1,
                                                   const short8* __restrict__ Bfr2,
                                                   const int* __restrict__ flag,
                                                   uint32_t* __restrict__ y2) {
    __shared__ float h1f[4][9][68];              // rows 0..7 = h1; row 8 = zeros; +4 pad
    int bf = *flag;
    int tid = threadIdx.x;
    int lane = tid & 63, wv = tid >> 6;
    int r8 = lane >> 3, wp = lane & 7;
    int g = blockIdx.x & 63, c = blockIdx.x >> 6;   // c in [0,32)
    int nbase = g * N_ + c * 32 + wv * 8;
    int cntv = cnt[nbase + wp];
    int offv = offs[nbase + wp];
    float isvv = inv_s[nbase + wp];
    int mskv = maskA[nbase + wp];
    int col = 8 * wp + ((lane >> 3) & 1) * 4 + ((lane >> 4) & 1) * 2 + ((lane >> 5) & 1);
    float bcol = ld1(b1, col, bf);
    h1f[wv][8][lane] = 0.f;                      // zero row for A-frag rows 8..15
    int idx = bucket[__shfl(offv, 0) + lane];    // prefetch node 0
    for (int i = 0; i < 8; ++i) {
        int node = nbase + i;
        int cnt_i = __shfl(cntv, i);
        int off_i = __shfl(offv, i);
        int msk_i = __shfl(mskv, i);
        int idx_cur = idx;
        if (i < 7) idx = bucket[__shfl(offv, i + 1) + lane];
        float hv = gather8(y1, bucket + off_i, idx_cur, cnt_i, msk_i, node, lane, r8, wp);
        float is = __shfl(isvv, i);
        float h = hv * is + bcol;
        h = (h >= 0.f) ? h : 0.01f * h;
        h1f[wv][i][col] = h;
    }
    // fused GEMM on a 16-row tile (rows 8..15 read the zero row)
    int m = lane & 15, q = lane >> 4;
    int mr = (m < 8) ? m : 8;
    short8 afr[2];
#pragma unroll
    for (int cc = 0; cc < 2; ++cc) {
        const float* rp = &h1f[wv][mr][cc * 32 + q * 8];
#pragma unroll
        for (int j = 0; j < 8; ++j) afr[cc][j] = to_bf(rp[j]);
    }
    f32x4 acc[4] = {};
#pragma unroll
    for (int nt = 0; nt < 4; ++nt)
#pragma unroll
        for (int cc = 0; cc < 2; ++cc)
            acc[nt] = __builtin_amdgcn_mfma_f32_16x16x32_bf16(afr[cc], Bfr2[(cc * 4 + nt) * 64 + lane], acc[nt], 0, 0, 0);
#pragma unroll
    for (int r = 0; r < 4; ++r) {
        int tr = q * 4 + r;                      // tile row = node offset
        if (tr < 8) {
            int node = nbase + tr;
            float is = __shfl(isvv, tr);
#pragma unroll
            for (int nt = 0; nt < 4; ++nt) {
                float v = acc[nt][r] * is;
                float vh = __shfl(v, lane + 1);
                if ((m & 1) == 0)
                    y2[(size_t)node * 32 + nt * 8 + (m >> 1)] = pack_bf2(v, vh);
            }
        }
    }
}

// ---------------- layer2: pure gather + pooling (one column per lane) ----------------
__global__ __launch_bounds__(256, 8) void k_layer2(const uint32_t* __restrict__ y2,
                                                   const float* __restrict__ inv_s,
                                                   const int* __restrict__ cnt,
                                                   const int* __restrict__ offs,
                                                   const int* __restrict__ maskA,
                                                   const int* __restrict__ bucket,
                                                   const void* __restrict__ b2,
                                                   const int* __restrict__ flag,
                                                   float* __restrict__ graph_sum) {
    int bf = *flag;
    int tid = threadIdx.x;
    int lane = tid & 63, wv = tid >> 6;
    int r8 = lane >> 3, wp = lane & 7;
    int g = blockIdx.x & 63, c = blockIdx.x >> 6;   // c in [0,32)
    int nbase = g * N_ + c * 32 + wv * 8;
    int cntv = cnt[nbase + wp];
    int offv = offs[nbase + wp];
    float isvv = inv_s[nbase + wp];
    int mskv = maskA[nbase + wp];
    int col = 8 * wp + ((lane >> 3) & 1) * 4 + ((lane >> 4) & 1) * 2 + ((lane >> 5) & 1);
    float bcol = ld1(b2, col, bf);
    int idx = bucket[__shfl(offv, 0) + lane];
    float pacc = 0.f;
    for (int i = 0; i < 8; ++i) {
        int node = nbase + i;
        int cnt_i = __shfl(cntv, i);
        int off_i = __shfl(offv, i);
        int msk_i = __shfl(mskv, i);
        int idx_cur = idx;
        if (i < 7) idx = bucket[__shfl(offv, i + 1) + lane];
        float hv = gather8(y2, bucket + off_i, idx_cur, cnt_i, msk_i, node, lane, r8, wp);
        float is = __shfl(isvv, i);
        pacc += hv * is + bcol;
    }
    atomicAdd(&graph_sum[g * H_ + col], pacc);
}

// ---------------- pooled emb -> answering head -> softmax ----------------
__global__ __launch_bounds__(64) void k_final(const float* __restrict__ graph_sum,
                                              const float* __restrict__ tok_sum,
                                              const void* __restrict__ Wa,
                                              const void* __restrict__ ba,
                                              const int* __restrict__ flag,
                                              void* __restrict__ out) {
    int bf = *flag;
    int b = blockIdx.x, l = threadIdx.x;
    float e = (tok_sum[l] + graph_sum[b * H_ + l]) * (1.0f / 1034.0f);
    float p0 = e * ld1(Wa, l * 2 + 0, bf);
    float p1 = e * ld1(Wa, l * 2 + 1, bf);
#pragma unroll
    for (int d = 32; d >= 1; d >>= 1) {
        p0 += __shfl_xor(p0, d);
        p1 += __shfl_xor(p1, d);
    }
    if (l == 0) {
        float l0 = p0 + ld1(ba, 0, bf);
        float l1 = p1 + ld1(ba, 1, bf);
        float mx = fmaxf(l0, l1);
        float e0 = expf(l0 - mx), e1 = expf(l1 - mx);
        float s = e0 + e1;
        float o0 = e0 / s, o1 = e1 / s;
        if (bf) {
            ((__hip_bfloat16*)out)[b * 2 + 0] = __float2bfloat16(o0);
            ((__hip_bfloat16*)out)[b * 2 + 1] = __float2bfloat16(o1);
        } else {
            ((float*)out)[b * 2 + 0] = o0;
            ((float*)out)[b * 2 + 1] = o1;
        }
    }
}

extern "C" void kernel_launch(void* const* d_in, const int* in_sizes, int n_in,
                              void* d_out, int out_size, void* d_ws, size_t ws_size,
                              hipStream_t stream) {
    (void)in_sizes; (void)n_in; (void)out_size; (void)ws_size;
    const void* x      = d_in[0];
    const void* tokens = d_in[1];
    const void* W1     = d_in[2];
    const void* b1     = d_in[3];
    const void* W2     = d_in[4];
    const void* b2     = d_in[5];
    const void* Wa     = d_in[6];
    const void* ba     = d_in[7];
    const int* esrc = (const int*)d_in[8];
    const int* edst = (const int*)d_in[9];

    char* w = (char*)d_ws;
    auto alloc = [&](size_t bytes) { void* p = (void*)w; w += (bytes + 255) & ~(size_t)255; return p; };
    int*      cnt       = (int*)alloc(BN * 4);
    int*      offs      = (int*)alloc(BN * 4);
    int*      maskA     = (int*)alloc(BN * 4);
    float*    inv_s     = (float*)alloc(BN * 4);
    int*      bucket    = (int*)alloc((size_t)BE * 4 + 512);            // 4 MB dense CSR
    uint32_t* y1        = (uint32_t*)alloc((size_t)(BN + 12) * 32 * 4); // node rows + pad row BN + P rows BN+1..BN+10
    uint32_t* y2        = (uint32_t*)alloc((size_t)(BN + 12) * 32 * 4);
    float*    tok_sum   = (float*)alloc(H_ * 4);
    float*    graph_sum = (float*)alloc(B_ * H_ * 4);
    short8*   Bfr       = (short8*)alloc(4 * 5 * 64 * sizeof(short8));
    short8*   Bfr2      = (short8*)alloc(2 * 4 * 64 * sizeof(short8));
    int*      dflag     = (int*)alloc(256);

    k_bucket   <<<B_, 1024, 0, stream>>>(esrc, edst, cnt, offs, bucket, graph_sum,
                                         y1 + (size_t)BN * 32, y2 + (size_t)BN * 32);
    k_prep     <<<7, 256, 0, stream>>>(W1, W2, tokens, dflag, Bfr, Bfr2);
    k_tok      <<<1, 64, 0, stream>>>(tokens, b1, b2, Bfr, Bfr2, dflag, y1, y2, tok_sum);
    k_node_mfma<<<BN / 64, 256, 0, stream>>>(x, Bfr, cnt, dflag, y1, inv_s, maskA);
    k_layer1   <<<BN / 32, 256, 0, stream>>>(y1, inv_s, cnt, offs, maskA, bucket, b1, Bfr2, dflag, y2);
    k_layer2   <<<BN / 32, 256, 0, stream>>>(y2, inv_s, cnt, offs, maskA, bucket, b2, dflag, graph_sum);
    k_final    <<<B_, 64, 0, stream>>>(graph_sum, tok_sum, Wa, ba, dflag, d_out);
}

// Round 2
// 200.886 us; speedup vs baseline: 1.4188x; 1.4188x over previous
//
#include <hip/hip_runtime.h>
#include <hip/hip_bf16.h>
#include <stdint.h>

#define B_ 64
#define N_ 1024
#define E_ 16384
#define F_ 128
#define H_ 64
#define T_ 10
#define BN (B_*N_)   // 65536
#define BE (B_*E_)   // 1048576

// sigmoid(z) >= p  <=>  z >= log(p/(1-p))
#define TH_INNER (-0.84729786f)   // logit(0.3)
#define TH_CROSS (-2.1972246f)    // logit(0.1)

typedef __attribute__((ext_vector_type(8))) short short8;  // bf16x8 MFMA frag
typedef __attribute__((ext_vector_type(4))) float f32x4;   // MFMA acc

__device__ __forceinline__ float ld1(const void* p, int i, int bf) {
    if (bf) {
        uint16_t u = ((const uint16_t*)p)[i];
        return __uint_as_float(((uint32_t)u) << 16);
    }
    return ((const float*)p)[i];
}

__device__ __forceinline__ short to_bf(float x) {
    return (short)__bfloat16_as_ushort(__float2bfloat16(x));
}

__device__ __forceinline__ uint32_t pack_bf2(float lo, float hi) {
    uint32_t l = (uint32_t)__bfloat16_as_ushort(__float2bfloat16(lo));
    uint32_t h = (uint32_t)__bfloat16_as_ushort(__float2bfloat16(hi));
    return l | (h << 16);
}

__device__ __forceinline__ float bflo(uint32_t u) { return __uint_as_float(u << 16); }
__device__ __forceinline__ float bfhi(uint32_t u) { return __uint_as_float(u & 0xffff0000u); }

// ---------------- block-per-graph: count -> wave scan -> dense CSR scatter ----------------
__global__ __launch_bounds__(1024) void k_bucket(const int* __restrict__ src,
                                                 const int* __restrict__ dst,
                                                 int* __restrict__ cnt,
                                                 int* __restrict__ offs,
                                                 int* __restrict__ bucket,
                                                 float* __restrict__ gsum,
                                                 uint32_t* __restrict__ y1pad,
                                                 uint32_t* __restrict__ y2pad) {
    __shared__ int lcnt[N_];
    __shared__ int wsum[16];
    int g = blockIdx.x, t = threadIdx.x;
    lcnt[t] = 0;
    if (t < 64) gsum[g * 64 + t] = 0.f;           // zero this graph's pool row
    if (g == 0) {                                 // zero pad rows once
        if (t < 32) y1pad[t] = 0;
        else if (t < 64) y2pad[t - 32] = 0;
    }
    __syncthreads();
#pragma unroll
    for (int it = 0; it < 16; ++it) {
        int i = g * E_ + it * 1024 + t;
        atomicAdd(&lcnt[dst[i]], 1);
    }
    __syncthreads();
    int v = lcnt[t];
    int sc = v;                                    // wave-level inclusive scan
#pragma unroll
    for (int d = 1; d < 64; d <<= 1) {
        int u = __shfl_up(sc, d);
        if ((t & 63) >= d) sc += u;
    }
    if ((t & 63) == 63) wsum[t >> 6] = sc;
    __syncthreads();
    if (t < 16) {                                  // scan the 16 wave sums
        int wsc = wsum[t];
#pragma unroll
        for (int d = 1; d < 16; d <<= 1) {
            int u = __shfl_up(wsc, d);
            if (t >= d) wsc += u;
        }
        wsum[t] = wsc;
    }
    __syncthreads();
    int base = sc - v + ((t >= 64) ? wsum[(t >> 6) - 1] : 0);  // exclusive prefix
    cnt[g * N_ + t] = v;
    offs[g * N_ + t] = g * E_ + base;             // absolute offset into bucket
    lcnt[t] = base;                               // reuse as within-graph cursor
    __syncthreads();
#pragma unroll
    for (int it = 0; it < 16; ++it) {
        int i = g * E_ + it * 1024 + t;
        int d = dst[i];
        int p = atomicAdd(&lcnt[d], 1);
        bucket[(size_t)g * E_ + p] = g * N_ + src[i];
    }
}

// ---------------- B fragments (W1|tokens^T and W2) + publish dtype flag ----------------
__global__ __launch_bounds__(256) void k_prep(const void* __restrict__ W1,
                                              const void* __restrict__ W2,
                                              const void* __restrict__ tokens,
                                              int* __restrict__ flag,
                                              short8* __restrict__ Bfr,
                                              short8* __restrict__ Bfr2) {
    uint32_t du = ((const uint32_t*)tokens)[threadIdx.x & 63];
    float dlo = __uint_as_float(du << 16);
    unsigned long long vote = __ballot(fabsf(dlo) <= 1.0f);
    int bf = (vote == ~0ull) ? 1 : 0;
    if (blockIdx.x == 0 && threadIdx.x == 0) *flag = bf;

    int f = blockIdx.x * 256 + threadIdx.x;      // [0, 1792)
    if (f < 1280) {                              // Bfr: [128 x 80] = W1 | tokens^T
        int c = f / 320, rem = f % 320;
        int nt = rem / 64, lane = rem % 64;
        int q = lane >> 4, n = nt * 16 + (lane & 15);
        int k0 = c * 32 + q * 8;
        short8 v;
#pragma unroll
        for (int j = 0; j < 8; ++j) {
            int k = k0 + j;
            float x = 0.f;
            if (n < H_) x = ld1(W1, k * H_ + n, bf);
            else if (n < H_ + T_) x = ld1(tokens, (n - H_) * F_ + k, bf);
            v[j] = to_bf(x);
        }
        Bfr[f] = v;
    } else {                                     // Bfr2: W2 [64 x 64]
        int f2 = f - 1280;
        int c = f2 / 256, rem = f2 % 256;
        int nt = rem / 64, lane = rem % 64;
        int q = lane >> 4, n = nt * 16 + (lane & 15);
        int k0 = c * 32 + q * 8;
        short8 v;
#pragma unroll
        for (int j = 0; j < 8; ++j) v[j] = to_bf(ld1(W2, (k0 + j) * H_ + n, bf));
        Bfr2[f2] = v;
    }
}

// ---------------- token stream via MFMA (1 wave); writes P rows into y1/y2 ----------------
__global__ __launch_bounds__(64) void k_tok(const void* __restrict__ tokens,
                                            const void* __restrict__ b1,
                                            const void* __restrict__ b2,
                                            const short8* __restrict__ Bfr,
                                            const short8* __restrict__ Bfr2,
                                            const int* __restrict__ flag,
                                            uint32_t* __restrict__ y1,
                                            uint32_t* __restrict__ y2,
                                            float* __restrict__ tok_sum) {
    __shared__ float nm[T_ * 16];
    __shared__ float ist_s[16], idt_s[16];
    __shared__ float htbuf[T_ * 64];
    __shared__ float h1s[T_ * 64];
    int bf = *flag;
    int l = threadIdx.x;
    int m = l & 15, q = l >> 4;
    int mrow = (m < T_) ? m : (T_ - 1);
    short8 afr[4];
    if (bf) {
        const short8* ar = (const short8*)((const uint16_t*)tokens + mrow * F_);
#pragma unroll
        for (int c = 0; c < 4; ++c) afr[c] = ar[c * 4 + q];
    } else {
        const float* ar = (const float*)tokens + mrow * F_;
#pragma unroll
        for (int c = 0; c < 4; ++c)
#pragma unroll
            for (int j = 0; j < 8; ++j) afr[c][j] = to_bf(ar[c * 32 + q * 8 + j]);
    }
    f32x4 accM = {};
    f32x4 acc1[4] = {};
#pragma unroll
    for (int c = 0; c < 4; ++c) {
        accM = __builtin_amdgcn_mfma_f32_16x16x32_bf16(afr[c], Bfr[(c * 5 + 4) * 64 + l], accM, 0, 0, 0);
#pragma unroll
        for (int nt = 0; nt < 4; ++nt)
            acc1[nt] = __builtin_amdgcn_mfma_f32_16x16x32_bf16(afr[c], Bfr[(c * 5 + nt) * 64 + l], acc1[nt], 0, 0, 0);
    }
    int cnt = 0;
#pragma unroll
    for (int r = 0; r < 4; ++r) {
        int row = q * 4 + r;
        if (row < T_ && m < T_ && accM[r] >= TH_INNER) cnt++;
    }
    cnt += __shfl_xor(cnt, 16);
    cnt += __shfl_xor(cnt, 32);
    float deg = 1.f + (float)cnt;
    float istc = 1.f / sqrtf(deg);
    float idtc = 1.f / deg;
    if (q == 0 && m < T_) { ist_s[m] = istc; idt_s[m] = idtc; }
#pragma unroll
    for (int nt = 0; nt < 4; ++nt)
#pragma unroll
        for (int r = 0; r < 4; ++r) {
            int row = q * 4 + r;
            if (row < T_) htbuf[row * 64 + nt * 16 + m] = acc1[nt][r];
        }
    __syncthreads();
    if (m < T_) {
#pragma unroll
        for (int r = 0; r < 4; ++r) {
            int row = q * 4 + r;
            if (row < T_)
                nm[row * 16 + m] = (accM[r] >= TH_INNER) ? ist_s[row] * istc : 0.f;
        }
    }
    __syncthreads();
    float htc[T_];
#pragma unroll
    for (int s = 0; s < T_; ++s) htc[s] = htbuf[s * 64 + l];
    float b1f = ld1(b1, l, bf);
#pragma unroll
    for (int t = 0; t < T_; ++t) {
        float a = htc[t] * idt_s[t] + b1f;
#pragma unroll
        for (int s = 0; s < T_; ++s) a += nm[t * 16 + s] * htc[s];
        a = (a >= 0.f) ? a : 0.01f * a;
        h1s[t * 64 + l] = a;
        float v = ist_s[t] * htc[t];              // P1 row -> y1[BN+1+t]
        float vh = __shfl(v, l + 1);
        if ((l & 1) == 0) y1[(size_t)(BN + 1 + t) * 32 + (l >> 1)] = pack_bf2(v, vh);
    }
    __syncthreads();
    short8 a2fr[2];
#pragma unroll
    for (int c = 0; c < 2; ++c)
#pragma unroll
        for (int j = 0; j < 8; ++j) a2fr[c][j] = to_bf(h1s[mrow * 64 + c * 32 + q * 8 + j]);
    f32x4 acc2[4] = {};
#pragma unroll
    for (int nt = 0; nt < 4; ++nt)
#pragma unroll
        for (int c = 0; c < 2; ++c)
            acc2[nt] = __builtin_amdgcn_mfma_f32_16x16x32_bf16(a2fr[c], Bfr2[(c * 4 + nt) * 64 + l], acc2[nt], 0, 0, 0);
#pragma unroll
    for (int nt = 0; nt < 4; ++nt)
#pragma unroll
        for (int r = 0; r < 4; ++r) {
            int row = q * 4 + r;
            if (row < T_) htbuf[row * 64 + nt * 16 + m] = acc2[nt][r];
        }
    __syncthreads();
    float b2f = ld1(b2, l, bf);
#pragma unroll
    for (int s = 0; s < T_; ++s) htc[s] = htbuf[s * 64 + l];
    float ts = 0.f;
#pragma unroll
    for (int t = 0; t < T_; ++t) {
        float o = htc[t] * idt_s[t] + b2f;
#pragma unroll
        for (int s = 0; s < T_; ++s) o += nm[t * 16 + s] * htc[s];
        ts += o;
        float v = ist_s[t] * htc[t];              // P2 row -> y2[BN+1+t]
        float vh = __shfl(v, l + 1);
        if ((l & 1) == 0) y2[(size_t)(BN + 1 + t) * 32 + (l >> 1)] = pack_bf2(v, vh);
    }
    tok_sum[l] = ts;
}

// ---------------- node GEMM: y1 + token-mask store + inv_s (no CSR appends) ----------------
__global__ __launch_bounds__(256) void k_node_mfma(const void* __restrict__ x,
                                                   const short8* __restrict__ Bfr,
                                                   const int* __restrict__ cnt,
                                                   const int* __restrict__ flag,
                                                   uint32_t* __restrict__ y1,
                                                   float* __restrict__ inv_s,
                                                   int* __restrict__ maskA) {
    int bf = *flag;
    int tid = threadIdx.x;
    int lane = tid & 63, wv = tid >> 6;
    int g = blockIdx.x & 63, c = blockIdx.x >> 6;   // XCD swizzle
    int row0 = g * N_ + c * 64 + wv * 16;
    int m = lane & 15, q = lane >> 4;
    int row = row0 + m;
    short8 afr[4];
    if (bf) {
        const short8* ar = (const short8*)((const uint16_t*)x + (size_t)row * F_);
#pragma unroll
        for (int cc = 0; cc < 4; ++cc) afr[cc] = ar[cc * 4 + q];
    } else {
        const float* ar = (const float*)x + (size_t)row * F_;
#pragma unroll
        for (int cc = 0; cc < 4; ++cc)
#pragma unroll
            for (int j = 0; j < 8; ++j)
                afr[cc][j] = to_bf(ar[cc * 32 + q * 8 + j]);
    }
    f32x4 acc[5] = {};
#pragma unroll
    for (int nt = 0; nt < 5; ++nt)
#pragma unroll
        for (int cc = 0; cc < 4; ++cc) {
            short8 bfr = Bfr[(cc * 5 + nt) * 64 + lane];
            acc[nt] = __builtin_amdgcn_mfma_f32_16x16x32_bf16(afr[cc], bfr, acc[nt], 0, 0, 0);
        }
    unsigned long long bal[4];
#pragma unroll
    for (int r = 0; r < 4; ++r) {
        int pred = (m < T_) && (acc[4][r] >= TH_CROSS);
        bal[r] = __ballot(pred);
    }
    float isv[4];
#pragma unroll
    for (int r = 0; r < 4; ++r) {
        int node = row0 + q * 4 + r;
        int mk = (int)((bal[r] >> (q * 16)) & 0x3FF);
        int ec = cnt[node];
        int pc = __popc((unsigned)mk);
        float deg = 1.f + (float)ec + (float)pc;
        isv[r] = 1.f / sqrtf(deg);
        if (m == 0) { inv_s[node] = isv[r]; maskA[node] = mk; }
    }
#pragma unroll
    for (int r = 0; r < 4; ++r) {
        int node = row0 + q * 4 + r;
#pragma unroll
        for (int nt = 0; nt < 4; ++nt) {
            float v = acc[nt][r] * isv[r];
            float vh = __shfl(v, lane + 1);
            if ((m & 1) == 0)
                y1[(size_t)node * 32 + nt * 8 + (m >> 1)] = pack_bf2(v, vh);
        }
    }
}

// ---------------- dwordx4 gather: 8 rows/instr, predicated (no pad reads),
// ---------------- reduce-scatter butterfly -> one output column per lane ----------------
__device__ __forceinline__ float gather8(const uint32_t* __restrict__ yu,
                                         const int* __restrict__ brow,
                                         int idx_cur, int cnt,
                                         int lane, int r8, int wp) {
    float a0 = 0.f, a1 = 0.f, a2 = 0.f, a3 = 0.f;
    float a4 = 0.f, a5 = 0.f, a6 = 0.f, a7 = 0.f;
    int eb = 0;
    while (true) {
        int cbat = min(cnt - eb, 64);
#pragma unroll
        for (int half = 0; half < 64; half += 32) {
            if (half < cbat) {
#pragma unroll
                for (int j = 0; j < 4; ++j) {
                    int e = half + 8 * j + r8;
                    int sv = __shfl(idx_cur, e & 63);
                    if (e < cbat) {               // uniform within 8-lane group -> exec mask
                        uint4 u = ((const uint4*)(yu + (size_t)sv * 32))[wp];
                        a0 += bflo(u.x); a1 += bfhi(u.x);
                        a2 += bflo(u.y); a3 += bfhi(u.y);
                        a4 += bflo(u.z); a5 += bfhi(u.z);
                        a6 += bflo(u.w); a7 += bfhi(u.w);
                    }
                }
            }
        }
        eb += 64;
        if (eb >= cnt) break;
        idx_cur = brow[eb + lane];               // rare (cnt > 64)
    }
    // reduce-scatter over row-lane groups (xor 8,16,32): lane ends with col
    // col = 8*wp + 4*b3 + 2*b4 + b5
    bool h8 = (lane & 8) != 0;
    float k0 = h8 ? a4 : a0, s0v = h8 ? a0 : a4;
    float k1 = h8 ? a5 : a1, s1v = h8 ? a1 : a5;
    float k2 = h8 ? a6 : a2, s2v = h8 ? a2 : a6;
    float k3 = h8 ? a7 : a3, s3v = h8 ? a3 : a7;
    k0 += __shfl_xor(s0v, 8);
    k1 += __shfl_xor(s1v, 8);
    k2 += __shfl_xor(s2v, 8);
    k3 += __shfl_xor(s3v, 8);
    bool h16 = (lane & 16) != 0;
    float m0 = h16 ? k2 : k0, n0 = h16 ? k0 : k2;
    float m1 = h16 ? k3 : k1, n1 = h16 ? k1 : k3;
    m0 += __shfl_xor(n0, 16);
    m1 += __shfl_xor(n1, 16);
    bool h32 = (lane & 32) != 0;
    float r0 = h32 ? m1 : m0, rs = h32 ? m0 : m1;
    r0 += __shfl_xor(rs, 32);
    return r0;
}

// per-lane column after the butterfly
__device__ __forceinline__ int col_of(int lane) {
    return 8 * (lane & 7) + ((lane >> 3) & 1) * 4 + ((lane >> 4) & 1) * 2 + ((lane >> 5) & 1);
}

// lane-local bf16 element at [row][col] of a packed y row
__device__ __forceinline__ float y_at(const uint32_t* __restrict__ yu, int row, int col) {
    uint32_t u = yu[(size_t)row * 32 + (col >> 1)];
    return (col & 1) ? bfhi(u) : bflo(u);
}

// ---------------- layer1: 8 nodes/wave gather + epilogue + fused h1@W2 -> y2 ----------------
__global__ __launch_bounds__(256, 6) void k_layer1(const uint32_t* __restrict__ y1,
                                                   const float* __restrict__ inv_s,
                                                   const int* __restrict__ cnt,
                                                   const int* __restrict__ offs,
                                                   const int* __restrict__ maskA,
                                                   const int* __restrict__ bucket,
                                                   const void* __restrict__ b1,
                                                   const short8* __restrict__ Bfr2,
                                                   const int* __restrict__ flag,
                                                   uint32_t* __restrict__ y2) {
    __shared__ float h1f[4][9][68];              // rows 0..7 = h1; row 8 = zeros; +4 pad
    int bf = *flag;
    int tid = threadIdx.x;
    int lane = tid & 63, wv = tid >> 6;
    int r8 = lane >> 3, wp = lane & 7;
    int g = blockIdx.x & 63, c = blockIdx.x >> 6;   // c in [0,32); graph g stays on XCD g%8
    int nbase = g * N_ + c * 32 + wv * 8;
    int cntv = cnt[nbase + wp];
    int offv = offs[nbase + wp];
    float isvv = inv_s[nbase + wp];
    int mskv = maskA[nbase + wp];
    int col = col_of(lane);
    float bcol = ld1(b1, col, bf);
    float tokv[T_];                              // token P1 values for this lane's col (once/wave)
#pragma unroll
    for (int t = 0; t < T_; ++t) tokv[t] = y_at(y1, BN + 1 + t, col);
    h1f[wv][8][lane] = 0.f;                      // zero row for A-frag rows 8..15
    int idx = 0;
    { int c0 = __shfl(cntv, 0); if (lane < c0) idx = bucket[__shfl(offv, 0) + lane]; }
    for (int i = 0; i < 8; ++i) {
        int node = nbase + i;
        int cnt_i = __shfl(cntv, i);
        int off_i = __shfl(offv, i);
        int msk_i = __shfl(mskv, i);
        int idx_cur = idx;
        if (i < 7) {
            int cn = __shfl(cntv, i + 1);
            if (lane < cn) idx = bucket[__shfl(offv, i + 1) + lane];
        }
        float hv = gather8(y1, bucket + off_i, idx_cur, cnt_i, lane, r8, wp);
        hv += y_at(y1, node, col);               // self loop (row already inv_s-scaled)
#pragma unroll
        for (int t = 0; t < T_; ++t)             // virtual token edges from registers
            hv += ((msk_i >> t) & 1) ? tokv[t] : 0.f;
        float is = __shfl(isvv, i);
        float h = hv * is + bcol;
        h = (h >= 0.f) ? h : 0.01f * h;
        h1f[wv][i][col] = h;
    }
    // fused GEMM on a 16-row tile (rows 8..15 read the zero row)
    int m = lane & 15, q = lane >> 4;
    int mr = (m < 8) ? m : 8;
    short8 afr[2];
#pragma unroll
    for (int cc = 0; cc < 2; ++cc) {
        const float* rp = &h1f[wv][mr][cc * 32 + q * 8];
#pragma unroll
        for (int j = 0; j < 8; ++j) afr[cc][j] = to_bf(rp[j]);
    }
    f32x4 acc[4] = {};
#pragma unroll
    for (int nt = 0; nt < 4; ++nt)
#pragma unroll
        for (int cc = 0; cc < 2; ++cc)
            acc[nt] = __builtin_amdgcn_mfma_f32_16x16x32_bf16(afr[cc], Bfr2[(cc * 4 + nt) * 64 + lane], acc[nt], 0, 0, 0);
#pragma unroll
    for (int r = 0; r < 4; ++r) {
        int tr = q * 4 + r;                      // tile row = node offset
        if (tr < 8) {
            int node = nbase + tr;
            float is = __shfl(isvv, tr);
#pragma unroll
            for (int nt = 0; nt < 4; ++nt) {
                float v = acc[nt][r] * is;
                float vh = __shfl(v, lane + 1);
                if ((m & 1) == 0)
                    y2[(size_t)node * 32 + nt * 8 + (m >> 1)] = pack_bf2(v, vh);
            }
        }
    }
}

// ---------------- layer2: pure gather + pooling (one column per lane) ----------------
__global__ __launch_bounds__(256, 8) void k_layer2(const uint32_t* __restrict__ y2,
                                                   const float* __restrict__ inv_s,
                                                   const int* __restrict__ cnt,
                                                   const int* __restrict__ offs,
                                                   const int* __restrict__ maskA,
                                                   const int* __restrict__ bucket,
                                                   const void* __restrict__ b2,
                                                   const int* __restrict__ flag,
                                                   float* __restrict__ graph_sum) {
    __shared__ float pool[4][64];
    int bf = *flag;
    int tid = threadIdx.x;
    int lane = tid & 63, wv = tid >> 6;
    int r8 = lane >> 3, wp = lane & 7;
    int g = blockIdx.x & 63, c = blockIdx.x >> 6;   // c in [0,32)
    int nbase = g * N_ + c * 32 + wv * 8;
    int cntv = cnt[nbase + wp];
    int offv = offs[nbase + wp];
    float isvv = inv_s[nbase + wp];
    int mskv = maskA[nbase + wp];
    int col = col_of(lane);
    float bcol = ld1(b2, col, bf);
    float tokv[T_];                              // token P2 values for this lane's col (once/wave)
#pragma unroll
    for (int t = 0; t < T_; ++t) tokv[t] = y_at(y2, BN + 1 + t, col);
    int idx = 0;
    { int c0 = __shfl(cntv, 0); if (lane < c0) idx = bucket[__shfl(offv, 0) + lane]; }
    float pacc = 0.f;
    for (int i = 0; i < 8; ++i) {
        int node = nbase + i;
        int cnt_i = __shfl(cntv, i);
        int off_i = __shfl(offv, i);
        int msk_i = __shfl(mskv, i);
        int idx_cur = idx;
        if (i < 7) {
            int cn = __shfl(cntv, i + 1);
            if (lane < cn) idx = bucket[__shfl(offv, i + 1) + lane];
        }
        float hv = gather8(y2, bucket + off_i, idx_cur, cnt_i, lane, r8, wp);
        hv += y_at(y2, node, col);               // self loop
#pragma unroll
        for (int t = 0; t < T_; ++t)             // virtual token edges from registers
            hv += ((msk_i >> t) & 1) ? tokv[t] : 0.f;
        float is = __shfl(isvv, i);
        pacc += hv * is + bcol;
    }
    pool[wv][col] = pacc;                        // col is a bijection of lane
    __syncthreads();
    if (tid < 64) {
        float s = pool[0][tid] + pool[1][tid] + pool[2][tid] + pool[3][tid];
        atomicAdd(&graph_sum[g * H_ + tid], s);
    }
}

// ---------------- pooled emb -> answering head -> softmax ----------------
__global__ __launch_bounds__(64) void k_final(const float* __restrict__ graph_sum,
                                              const float* __restrict__ tok_sum,
                                              const void* __restrict__ Wa,
                                              const void* __restrict__ ba,
                                              const int* __restrict__ flag,
                                              void* __restrict__ out) {
    int bf = *flag;
    int b = blockIdx.x, l = threadIdx.x;
    float e = (tok_sum[l] + graph_sum[b * H_ + l]) * (1.0f / 1034.0f);
    float p0 = e * ld1(Wa, l * 2 + 0, bf);
    float p1 = e * ld1(Wa, l * 2 + 1, bf);
#pragma unroll
    for (int d = 32; d >= 1; d >>= 1) {
        p0 += __shfl_xor(p0, d);
        p1 += __shfl_xor(p1, d);
    }
    if (l == 0) {
        float l0 = p0 + ld1(ba, 0, bf);
        float l1 = p1 + ld1(ba, 1, bf);
        float mx = fmaxf(l0, l1);
        float e0 = expf(l0 - mx), e1 = expf(l1 - mx);
        float s = e0 + e1;
        float o0 = e0 / s, o1 = e1 / s;
        if (bf) {
            ((__hip_bfloat16*)out)[b * 2 + 0] = __float2bfloat16(o0);
            ((__hip_bfloat16*)out)[b * 2 + 1] = __float2bfloat16(o1);
        } else {
            ((float*)out)[b * 2 + 0] = o0;
            ((float*)out)[b * 2 + 1] = o1;
        }
    }
}

extern "C" void kernel_launch(void* const* d_in, const int* in_sizes, int n_in,
                              void* d_out, int out_size, void* d_ws, size_t ws_size,
                              hipStream_t stream) {
    (void)in_sizes; (void)n_in; (void)out_size; (void)ws_size;
    const void* x      = d_in[0];
    const void* tokens = d_in[1];
    const void* W1     = d_in[2];
    const void* b1     = d_in[3];
    const void* W2     = d_in[4];
    const void* b2     = d_in[5];
    const void* Wa     = d_in[6];
    const void* ba     = d_in[7];
    const int* esrc = (const int*)d_in[8];
    const int* edst = (const int*)d_in[9];

    char* w = (char*)d_ws;
    auto alloc = [&](size_t bytes) { void* p = (void*)w; w += (bytes + 255) & ~(size_t)255; return p; };
    int*      cnt       = (int*)alloc(BN * 4);
    int*      offs      = (int*)alloc(BN * 4);
    int*      maskA     = (int*)alloc(BN * 4);
    float*    inv_s     = (float*)alloc(BN * 4);
    int*      bucket    = (int*)alloc((size_t)BE * 4 + 512);            // 4 MB dense CSR
    uint32_t* y1        = (uint32_t*)alloc((size_t)(BN + 12) * 32 * 4); // node rows + pad row BN + P rows BN+1..BN+10
    uint32_t* y2        = (uint32_t*)alloc((size_t)(BN + 12) * 32 * 4);
    float*    tok_sum   = (float*)alloc(H_ * 4);
    float*    graph_sum = (float*)alloc(B_ * H_ * 4);
    short8*   Bfr       = (short8*)alloc(4 * 5 * 64 * sizeof(short8));
    short8*   Bfr2      = (short8*)alloc(2 * 4 * 64 * sizeof(short8));
    int*      dflag     = (int*)alloc(256);

    k_bucket   <<<B_, 1024, 0, stream>>>(esrc, edst, cnt, offs, bucket, graph_sum,
                                         y1 + (size_t)BN * 32, y2 + (size_t)BN * 32);
    k_prep     <<<7, 256, 0, stream>>>(W1, W2, tokens, dflag, Bfr, Bfr2);
    k_tok      <<<1, 64, 0, stream>>>(tokens, b1, b2, Bfr, Bfr2, dflag, y1, y2, tok_sum);
    k_node_mfma<<<BN / 64, 256, 0, stream>>>(x, Bfr, cnt, dflag, y1, inv_s, maskA);
    k_layer1   <<<BN / 32, 256, 0, stream>>>(y1, inv_s, cnt, offs, maskA, bucket, b1, Bfr2, dflag, y2);
    k_layer2   <<<BN / 32, 256, 0, stream>>>(y2, inv_s, cnt, offs, maskA, bucket, b2, dflag, graph_sum);
    k_final    <<<B_, 64, 0, stream>>>(graph_sum, tok_sum, Wa, ba, dflag, d_out);
}

// Round 4
// 184.192 us; speedup vs baseline: 1.5474x; 1.0906x over previous
//
#include <hip/hip_runtime.h>
#include <hip/hip_bf16.h>
#include <stdint.h>

#define B_ 64
#define N_ 1024
#define E_ 16384
#define F_ 128
#define H_ 64
#define T_ 10
#define BN (B_*N_)   // 65536
#define BE (B_*E_)   // 1048576

// sigmoid(z) >= p  <=>  z >= log(p/(1-p))
#define TH_INNER (-0.84729786f)   // logit(0.3)
#define TH_CROSS (-2.1972246f)    // logit(0.1)

typedef __attribute__((ext_vector_type(8))) short short8;  // bf16x8 MFMA frag
typedef __attribute__((ext_vector_type(4))) float f32x4;   // MFMA acc

__device__ __forceinline__ float ld1(const void* p, int i, int bf) {
    if (bf) {
        uint16_t u = ((const uint16_t*)p)[i];
        return __uint_as_float(((uint32_t)u) << 16);
    }
    return ((const float*)p)[i];
}

__device__ __forceinline__ short to_bf(float x) {
    return (short)__bfloat16_as_ushort(__float2bfloat16(x));
}

__device__ __forceinline__ uint32_t pack_bf2(float lo, float hi) {
    uint32_t l = (uint32_t)__bfloat16_as_ushort(__float2bfloat16(lo));
    uint32_t h = (uint32_t)__bfloat16_as_ushort(__float2bfloat16(hi));
    return l | (h << 16);
}

__device__ __forceinline__ float bflo(uint32_t u) { return __uint_as_float(u << 16); }
__device__ __forceinline__ float bfhi(uint32_t u) { return __uint_as_float(u & 0xffff0000u); }

// ---------------- block-per-graph: count -> wave scan -> dense CSR scatter ----------------
__global__ __launch_bounds__(1024) void k_bucket(const int* __restrict__ src,
                                                 const int* __restrict__ dst,
                                                 int* __restrict__ cnt,
                                                 int* __restrict__ offs,
                                                 int* __restrict__ bucket,
                                                 float* __restrict__ gsum,
                                                 uint32_t* __restrict__ y1pad,
                                                 uint32_t* __restrict__ y2pad) {
    __shared__ int lcnt[N_];
    __shared__ int wsum[16];
    int g = blockIdx.x, t = threadIdx.x;
    lcnt[t] = 0;
    if (t < 64) gsum[g * 64 + t] = 0.f;           // zero this graph's pool row
    if (g == 0) {                                 // zero pad rows once
        if (t < 32) y1pad[t] = 0;
        else if (t < 64) y2pad[t - 32] = 0;
    }
    __syncthreads();
    int dval[16];                                 // cache dst in VGPRs across passes
#pragma unroll
    for (int it = 0; it < 16; ++it) {
        dval[it] = dst[g * E_ + it * 1024 + t];
        atomicAdd(&lcnt[dval[it]], 1);
    }
    __syncthreads();
    int v = lcnt[t];
    int sc = v;                                    // wave-level inclusive scan
#pragma unroll
    for (int d = 1; d < 64; d <<= 1) {
        int u = __shfl_up(sc, d);
        if ((t & 63) >= d) sc += u;
    }
    if ((t & 63) == 63) wsum[t >> 6] = sc;
    __syncthreads();
    if (t < 16) {                                  // scan the 16 wave sums
        int wsc = wsum[t];
#pragma unroll
        for (int d = 1; d < 16; d <<= 1) {
            int u = __shfl_up(wsc, d);
            if (t >= d) wsc += u;
        }
        wsum[t] = wsc;
    }
    __syncthreads();
    int base = sc - v + ((t >= 64) ? wsum[(t >> 6) - 1] : 0);  // exclusive prefix
    cnt[g * N_ + t] = v;
    offs[g * N_ + t] = g * E_ + base;             // absolute offset into bucket
    lcnt[t] = base;                               // reuse as within-graph cursor
    __syncthreads();
#pragma unroll
    for (int it = 0; it < 16; ++it) {
        int d = dval[it];
        int p = atomicAdd(&lcnt[d], 1);
        bucket[(size_t)g * E_ + p] = g * N_ + src[g * E_ + it * 1024 + t];
    }
}

// ---------------- B fragments (W1|tokens^T and W2) + publish dtype flag ----------------
__global__ __launch_bounds__(256) void k_prep(const void* __restrict__ W1,
                                              const void* __restrict__ W2,
                                              const void* __restrict__ tokens,
                                              int* __restrict__ flag,
                                              short8* __restrict__ Bfr,
                                              short8* __restrict__ Bfr2) {
    uint32_t du = ((const uint32_t*)tokens)[threadIdx.x & 63];
    float dlo = __uint_as_float(du << 16);
    unsigned long long vote = __ballot(fabsf(dlo) <= 1.0f);
    int bf = (vote == ~0ull) ? 1 : 0;
    if (blockIdx.x == 0 && threadIdx.x == 0) *flag = bf;

    int f = blockIdx.x * 256 + threadIdx.x;      // [0, 1792)
    if (f < 1280) {                              // Bfr: [128 x 80] = W1 | tokens^T
        int c = f / 320, rem = f % 320;
        int nt = rem / 64, lane = rem % 64;
        int q = lane >> 4, n = nt * 16 + (lane & 15);
        int k0 = c * 32 + q * 8;
        short8 v;
#pragma unroll
        for (int j = 0; j < 8; ++j) {
            int k = k0 + j;
            float x = 0.f;
            if (n < H_) x = ld1(W1, k * H_ + n, bf);
            else if (n < H_ + T_) x = ld1(tokens, (n - H_) * F_ + k, bf);
            v[j] = to_bf(x);
        }
        Bfr[f] = v;
    } else {                                     // Bfr2: W2 [64 x 64]
        int f2 = f - 1280;
        int c = f2 / 256, rem = f2 % 256;
        int nt = rem / 64, lane = rem % 64;
        int q = lane >> 4, n = nt * 16 + (lane & 15);
        int k0 = c * 32 + q * 8;
        short8 v;
#pragma unroll
        for (int j = 0; j < 8; ++j) v[j] = to_bf(ld1(W2, (k0 + j) * H_ + n, bf));
        Bfr2[f2] = v;
    }
}

// ---------------- token stream via MFMA (1 wave); writes P rows into y1/y2 ----------------
__global__ __launch_bounds__(64) void k_tok(const void* __restrict__ tokens,
                                            const void* __restrict__ b1,
                                            const void* __restrict__ b2,
                                            const short8* __restrict__ Bfr,
                                            const short8* __restrict__ Bfr2,
                                            const int* __restrict__ flag,
                                            uint32_t* __restrict__ y1,
                                            uint32_t* __restrict__ y2,
                                            float* __restrict__ tok_sum) {
    __shared__ float nm[T_ * 16];
    __shared__ float ist_s[16], idt_s[16];
    __shared__ float htbuf[T_ * 64];
    __shared__ float h1s[T_ * 64];
    int bf = *flag;
    int l = threadIdx.x;
    int m = l & 15, q = l >> 4;
    int mrow = (m < T_) ? m : (T_ - 1);
    short8 afr[4];
    if (bf) {
        const short8* ar = (const short8*)((const uint16_t*)tokens + mrow * F_);
#pragma unroll
        for (int c = 0; c < 4; ++c) afr[c] = ar[c * 4 + q];
    } else {
        const float* ar = (const float*)tokens + mrow * F_;
#pragma unroll
        for (int c = 0; c < 4; ++c)
#pragma unroll
            for (int j = 0; j < 8; ++j) afr[c][j] = to_bf(ar[c * 32 + q * 8 + j]);
    }
    f32x4 accM = {};
    f32x4 acc1[4] = {};
#pragma unroll
    for (int c = 0; c < 4; ++c) {
        accM = __builtin_amdgcn_mfma_f32_16x16x32_bf16(afr[c], Bfr[(c * 5 + 4) * 64 + l], accM, 0, 0, 0);
#pragma unroll
        for (int nt = 0; nt < 4; ++nt)
            acc1[nt] = __builtin_amdgcn_mfma_f32_16x16x32_bf16(afr[c], Bfr[(c * 5 + nt) * 64 + l], acc1[nt], 0, 0, 0);
    }
    int cnt = 0;
#pragma unroll
    for (int r = 0; r < 4; ++r) {
        int row = q * 4 + r;
        if (row < T_ && m < T_ && accM[r] >= TH_INNER) cnt++;
    }
    cnt += __shfl_xor(cnt, 16);
    cnt += __shfl_xor(cnt, 32);
    float deg = 1.f + (float)cnt;
    float istc = 1.f / sqrtf(deg);
    float idtc = 1.f / deg;
    if (q == 0 && m < T_) { ist_s[m] = istc; idt_s[m] = idtc; }
#pragma unroll
    for (int nt = 0; nt < 4; ++nt)
#pragma unroll
        for (int r = 0; r < 4; ++r) {
            int row = q * 4 + r;
            if (row < T_) htbuf[row * 64 + nt * 16 + m] = acc1[nt][r];
        }
    __syncthreads();
    if (m < T_) {
#pragma unroll
        for (int r = 0; r < 4; ++r) {
            int row = q * 4 + r;
            if (row < T_)
                nm[row * 16 + m] = (accM[r] >= TH_INNER) ? ist_s[row] * istc : 0.f;
        }
    }
    __syncthreads();
    float htc[T_];
#pragma unroll
    for (int s = 0; s < T_; ++s) htc[s] = htbuf[s * 64 + l];
    float b1f = ld1(b1, l, bf);
#pragma unroll
    for (int t = 0; t < T_; ++t) {
        float a = htc[t] * idt_s[t] + b1f;
#pragma unroll
        for (int s = 0; s < T_; ++s) a += nm[t * 16 + s] * htc[s];
        a = (a >= 0.f) ? a : 0.01f * a;
        h1s[t * 64 + l] = a;
        float v = ist_s[t] * htc[t];              // P1 row -> y1[BN+1+t]
        float vh = __shfl(v, l + 1);
        if ((l & 1) == 0) y1[(size_t)(BN + 1 + t) * 32 + (l >> 1)] = pack_bf2(v, vh);
    }
    __syncthreads();
    short8 a2fr[2];
#pragma unroll
    for (int c = 0; c < 2; ++c)
#pragma unroll
        for (int j = 0; j < 8; ++j) a2fr[c][j] = to_bf(h1s[mrow * 64 + c * 32 + q * 8 + j]);
    f32x4 acc2[4] = {};
#pragma unroll
    for (int nt = 0; nt < 4; ++nt)
#pragma unroll
        for (int c = 0; c < 2; ++c)
            acc2[nt] = __builtin_amdgcn_mfma_f32_16x16x32_bf16(a2fr[c], Bfr2[(c * 4 + nt) * 64 + l], acc2[nt], 0, 0, 0);
#pragma unroll
    for (int nt = 0; nt < 4; ++nt)
#pragma unroll
        for (int r = 0; r < 4; ++r) {
            int row = q * 4 + r;
            if (row < T_) htbuf[row * 64 + nt * 16 + m] = acc2[nt][r];
        }
    __syncthreads();
    float b2f = ld1(b2, l, bf);
#pragma unroll
    for (int s = 0; s < T_; ++s) htc[s] = htbuf[s * 64 + l];
    float ts = 0.f;
#pragma unroll
    for (int t = 0; t < T_; ++t) {
        float o = htc[t] * idt_s[t] + b2f;
#pragma unroll
        for (int s = 0; s < T_; ++s) o += nm[t * 16 + s] * htc[s];
        ts += o;
        float v = ist_s[t] * htc[t];              // P2 row -> y2[BN+1+t]
        float vh = __shfl(v, l + 1);
        if ((l & 1) == 0) y2[(size_t)(BN + 1 + t) * 32 + (l >> 1)] = pack_bf2(v, vh);
    }
    tok_sum[l] = ts;
}

// ---------------- node GEMM: y1 + token-mask store + inv_s (no CSR appends) ----------------
__global__ __launch_bounds__(256) void k_node_mfma(const void* __restrict__ x,
                                                   const short8* __restrict__ Bfr,
                                                   const int* __restrict__ cnt,
                                                   const int* __restrict__ flag,
                                                   uint32_t* __restrict__ y1,
                                                   float* __restrict__ inv_s,
                                                   int* __restrict__ maskA) {
    int bf = *flag;
    int tid = threadIdx.x;
    int lane = tid & 63, wv = tid >> 6;
    int g = blockIdx.x & 63, c = blockIdx.x >> 6;   // XCD swizzle
    int row0 = g * N_ + c * 64 + wv * 16;
    int m = lane & 15, q = lane >> 4;
    int row = row0 + m;
    short8 afr[4];
    if (bf) {
        const short8* ar = (const short8*)((const uint16_t*)x + (size_t)row * F_);
#pragma unroll
        for (int cc = 0; cc < 4; ++cc) afr[cc] = ar[cc * 4 + q];
    } else {
        const float* ar = (const float*)x + (size_t)row * F_;
#pragma unroll
        for (int cc = 0; cc < 4; ++cc)
#pragma unroll
            for (int j = 0; j < 8; ++j)
                afr[cc][j] = to_bf(ar[cc * 32 + q * 8 + j]);
    }
    f32x4 acc[5] = {};
#pragma unroll
    for (int nt = 0; nt < 5; ++nt)
#pragma unroll
        for (int cc = 0; cc < 4; ++cc) {
            short8 bfr = Bfr[(cc * 5 + nt) * 64 + lane];
            acc[nt] = __builtin_amdgcn_mfma_f32_16x16x32_bf16(afr[cc], bfr, acc[nt], 0, 0, 0);
        }
    unsigned long long bal[4];
#pragma unroll
    for (int r = 0; r < 4; ++r) {
        int pred = (m < T_) && (acc[4][r] >= TH_CROSS);
        bal[r] = __ballot(pred);
    }
    float isv[4];
#pragma unroll
    for (int r = 0; r < 4; ++r) {
        int node = row0 + q * 4 + r;
        int mk = (int)((bal[r] >> (q * 16)) & 0x3FF);
        int ec = cnt[node];
        int pc = __popc((unsigned)mk);
        float deg = 1.f + (float)ec + (float)pc;
        isv[r] = 1.f / sqrtf(deg);
        if (m == 0) { inv_s[node] = isv[r]; maskA[node] = mk; }
    }
#pragma unroll
    for (int r = 0; r < 4; ++r) {
        int node = row0 + q * 4 + r;
#pragma unroll
        for (int nt = 0; nt < 4; ++nt) {
            float v = acc[nt][r] * isv[r];
            float vh = __shfl(v, lane + 1);
            if ((m & 1) == 0)
                y1[(size_t)node * 32 + nt * 8 + (m >> 1)] = pack_bf2(v, vh);
        }
    }
}

// ---------------- LDS-staged gather: rows live in LDS (group-XOR swizzled),
// ---------------- reduce-scatter butterfly -> one output column per lane ----------------
__device__ __forceinline__ float gather8_lds(const uint32_t* __restrict__ ys,
                                             const int* __restrict__ brow,
                                             int idx_cur, int cnt,
                                             int lane, int r8, int wp) {
    float a0 = 0.f, a1 = 0.f, a2 = 0.f, a3 = 0.f;
    float a4 = 0.f, a5 = 0.f, a6 = 0.f, a7 = 0.f;
    int eb = 0;
    while (true) {
        int cbat = min(cnt - eb, 64);
#pragma unroll
        for (int half = 0; half < 64; half += 32) {
            if (half < cbat) {
#pragma unroll
                for (int j = 0; j < 4; ++j) {
                    int e = half + 8 * j + r8;
                    int sv = __shfl(idx_cur, e & 63);
                    if (e < cbat) {               // uniform within 8-lane group -> exec mask
                        int sl = sv & (N_ - 1);
                        uint4 u = *(const uint4*)&ys[sl * 32 + ((wp ^ (sl & 7)) << 2)];
                        a0 += bflo(u.x); a1 += bfhi(u.x);
                        a2 += bflo(u.y); a3 += bfhi(u.y);
                        a4 += bflo(u.z); a5 += bfhi(u.z);
                        a6 += bflo(u.w); a7 += bfhi(u.w);
                    }
                }
            }
        }
        eb += 64;
        if (eb >= cnt) break;
        idx_cur = brow[eb + lane];               // rare (cnt > 64)
    }
    // reduce-scatter over row-lane groups (xor 8,16,32): lane ends with col
    // col = 8*wp + 4*b3 + 2*b4 + b5
    bool h8 = (lane & 8) != 0;
    float k0 = h8 ? a4 : a0, s0v = h8 ? a0 : a4;
    float k1 = h8 ? a5 : a1, s1v = h8 ? a1 : a5;
    float k2 = h8 ? a6 : a2, s2v = h8 ? a2 : a6;
    float k3 = h8 ? a7 : a3, s3v = h8 ? a3 : a7;
    k0 += __shfl_xor(s0v, 8);
    k1 += __shfl_xor(s1v, 8);
    k2 += __shfl_xor(s2v, 8);
    k3 += __shfl_xor(s3v, 8);
    bool h16 = (lane & 16) != 0;
    float m0 = h16 ? k2 : k0, n0 = h16 ? k0 : k2;
    float m1 = h16 ? k3 : k1, n1 = h16 ? k1 : k3;
    m0 += __shfl_xor(n0, 16);
    m1 += __shfl_xor(n1, 16);
    bool h32 = (lane & 32) != 0;
    float r0 = h32 ? m1 : m0, rs = h32 ? m0 : m1;
    r0 += __shfl_xor(rs, 32);
    return r0;
}

// per-lane column after the butterfly
__device__ __forceinline__ int col_of(int lane) {
    return 8 * (lane & 7) + ((lane >> 3) & 1) * 4 + ((lane >> 4) & 1) * 2 + ((lane >> 5) & 1);
}

// lane-local bf16 element at [row][col] of a packed GLOBAL y row
__device__ __forceinline__ float y_at(const uint32_t* __restrict__ yu, int row, int col) {
    uint32_t u = yu[(size_t)row * 32 + (col >> 1)];
    return (col & 1) ? bfhi(u) : bflo(u);
}

// stage one graph's 1024x128B y-slice into LDS with the group-XOR swizzle
__device__ __forceinline__ void stage_slice(uint32_t* __restrict__ ys,
                                            const uint32_t* __restrict__ yg,
                                            int tid) {
#pragma unroll
    for (int it = 0; it < 8; ++it) {
        int chunk = it * 1024 + tid;             // [0, 8192): 1024 rows x 8 groups
        int r = chunk >> 3, gg = chunk & 7;
        uint4 v = *(const uint4*)(yg + r * 32 + gg * 4);
        *(uint4*)&ys[r * 32 + ((gg ^ (r & 7)) << 2)] = v;
    }
}

// ---------------- layer1: per-graph LDS staging, 16 nodes/wave, fused h1@W2 -> y2 ----------------
__global__ __launch_bounds__(1024, 1) void k_layer1(const uint32_t* __restrict__ y1,
                                                    const float* __restrict__ inv_s,
                                                    const int* __restrict__ cnt,
                                                    const int* __restrict__ offs,
                                                    const int* __restrict__ maskA,
                                                    const int* __restrict__ bucket,
                                                    const void* __restrict__ b1,
                                                    const short8* __restrict__ Bfr2,
                                                    const int* __restrict__ flag,
                                                    uint32_t* __restrict__ y2) {
    __shared__ uint32_t y1s[N_ * 32];            // 128 KB staged slice (swizzled)
    __shared__ uint32_t h1w[16][9 * 36];         // bf16-packed h1 tiles; row 8 = zeros
    int bf = *flag;
    int tid = threadIdx.x;
    int lane = tid & 63, wv = tid >> 6;
    int r8 = lane >> 3, wp = lane & 7;
    int g = blockIdx.x & 63, c = blockIdx.x >> 6;   // 4 blocks/graph; graph g on XCD g%8
    stage_slice(y1s, y1 + (size_t)g * N_ * 32, tid);
    int nbase = g * N_ + c * 256 + wv * 16;
    int cntv = cnt[nbase + (lane & 15)];
    int offv = offs[nbase + (lane & 15)];
    float isvv = inv_s[nbase + (lane & 15)];
    int mskv = maskA[nbase + (lane & 15)];
    int col = col_of(lane);
    float bcol = ld1(b1, col, bf);
    float tokv[T_];                              // token P1 values for this lane's col
#pragma unroll
    for (int t = 0; t < T_; ++t) tokv[t] = y_at(y1, BN + 1 + t, col);
    if (lane < 36) h1w[wv][8 * 36 + lane] = 0;   // zero row for A-frag rows 8..15
    __syncthreads();
    int m = lane & 15, q = lane >> 4;
    int mr = (m < 8) ? m : 8;
    int idx = 0;
    { int c0 = __shfl(cntv, 0); if (lane < c0) idx = bucket[__shfl(offv, 0) + lane]; }
    for (int k = 0; k < 2; ++k) {
        for (int i = 0; i < 8; ++i) {
            int ni = k * 8 + i;
            int node = nbase + ni;
            int cnt_i = __shfl(cntv, ni);
            int off_i = __shfl(offv, ni);
            int msk_i = __shfl(mskv, ni);
            int idx_cur = idx;
            if (ni < 15) {
                int cn = __shfl(cntv, ni + 1);
                if (lane < cn) idx = bucket[__shfl(offv, ni + 1) + lane];
            }
            float hv = gather8_lds(y1s, bucket + off_i, idx_cur, cnt_i, lane, r8, wp);
            int nl = node & (N_ - 1);            // self loop from LDS (row pre-scaled)
            uint32_t su = y1s[nl * 32 + ((((col >> 3) ^ (nl & 7)) << 2) | ((col >> 1) & 3))];
            hv += (col & 1) ? bfhi(su) : bflo(su);
#pragma unroll
            for (int t = 0; t < T_; ++t)         // virtual token edges from registers
                hv += ((msk_i >> t) & 1) ? tokv[t] : 0.f;
            float is = __shfl(isvv, ni);
            float h = hv * is + bcol;
            h = (h >= 0.f) ? h : 0.01f * h;
            float hx = __shfl_xor(h, 32);        // partner col (b5 flip = col+-1)
            if ((lane & 32) == 0) h1w[wv][i * 36 + (col >> 1)] = pack_bf2(h, hx);
        }
        // fused GEMM on 8-node chunk (rows 8..15 read the zero row)
        short8 afr[2];
#pragma unroll
        for (int cc = 0; cc < 2; ++cc)
            afr[cc] = *(const short8*)&h1w[wv][mr * 36 + cc * 16 + q * 4];
        f32x4 acc[4] = {};
#pragma unroll
        for (int nt = 0; nt < 4; ++nt)
#pragma unroll
            for (int cc = 0; cc < 2; ++cc)
                acc[nt] = __builtin_amdgcn_mfma_f32_16x16x32_bf16(afr[cc], Bfr2[(cc * 4 + nt) * 64 + lane], acc[nt], 0, 0, 0);
#pragma unroll
        for (int r = 0; r < 4; ++r) {
            int tr = q * 4 + r;                  // tile row = node offset in chunk
            if (tr < 8) {
                int node = nbase + k * 8 + tr;
                float is = __shfl(isvv, k * 8 + tr);
#pragma unroll
                for (int nt = 0; nt < 4; ++nt) {
                    float v = acc[nt][r] * is;
                    float vh = __shfl(v, lane + 1);
                    if ((m & 1) == 0)
                        y2[(size_t)node * 32 + nt * 8 + (m >> 1)] = pack_bf2(v, vh);
                }
            }
        }
    }
}

// ---------------- layer2: per-graph LDS staging, gather + pooling ----------------
__global__ __launch_bounds__(1024, 1) void k_layer2(const uint32_t* __restrict__ y2,
                                                    const float* __restrict__ inv_s,
                                                    const int* __restrict__ cnt,
                                                    const int* __restrict__ offs,
                                                    const int* __restrict__ maskA,
                                                    const int* __restrict__ bucket,
                                                    const void* __restrict__ b2,
                                                    const int* __restrict__ flag,
                                                    float* __restrict__ graph_sum) {
    __shared__ uint32_t y2s[N_ * 32];            // 128 KB staged slice (swizzled)
    __shared__ float pool[16][64];
    int bf = *flag;
    int tid = threadIdx.x;
    int lane = tid & 63, wv = tid >> 6;
    int r8 = lane >> 3, wp = lane & 7;
    int g = blockIdx.x & 63, c = blockIdx.x >> 6;   // 4 blocks/graph
    stage_slice(y2s, y2 + (size_t)g * N_ * 32, tid);
    int nbase = g * N_ + c * 256 + wv * 16;
    int cntv = cnt[nbase + (lane & 15)];
    int offv = offs[nbase + (lane & 15)];
    float isvv = inv_s[nbase + (lane & 15)];
    int mskv = maskA[nbase + (lane & 15)];
    int col = col_of(lane);
    float bcol = ld1(b2, col, bf);
    float tokv[T_];                              // token P2 values for this lane's col
#pragma unroll
    for (int t = 0; t < T_; ++t) tokv[t] = y_at(y2, BN + 1 + t, col);
    __syncthreads();
    int idx = 0;
    { int c0 = __shfl(cntv, 0); if (lane < c0) idx = bucket[__shfl(offv, 0) + lane]; }
    float pacc = 0.f;
    for (int ni = 0; ni < 16; ++ni) {
        int node = nbase + ni;
        int cnt_i = __shfl(cntv, ni);
        int off_i = __shfl(offv, ni);
        int msk_i = __shfl(mskv, ni);
        int idx_cur = idx;
        if (ni < 15) {
            int cn = __shfl(cntv, ni + 1);
            if (lane < cn) idx = bucket[__shfl(offv, ni + 1) + lane];
        }
        float hv = gather8_lds(y2s, bucket + off_i, idx_cur, cnt_i, lane, r8, wp);
        int nl = node & (N_ - 1);                // self loop from LDS
        uint32_t su = y2s[nl * 32 + ((((col >> 3) ^ (nl & 7)) << 2) | ((col >> 1) & 3))];
        hv += (col & 1) ? bfhi(su) : bflo(su);
#pragma unroll
        for (int t = 0; t < T_; ++t)             // virtual token edges from registers
            hv += ((msk_i >> t) & 1) ? tokv[t] : 0.f;
        float is = __shfl(isvv, ni);
        pacc += hv * is + bcol;
    }
    pool[wv][col] = pacc;                        // col is a bijection of lane
    __syncthreads();
    if (tid < 64) {
        float s = 0.f;
#pragma unroll
        for (int w2 = 0; w2 < 16; ++w2) s += pool[w2][tid];
        atomicAdd(&graph_sum[g * H_ + tid], s);
    }
}

// ---------------- pooled emb -> answering head -> softmax ----------------
__global__ __launch_bounds__(64) void k_final(const float* __restrict__ graph_sum,
                                              const float* __restrict__ tok_sum,
                                              const void* __restrict__ Wa,
                                              const void* __restrict__ ba,
                                              const int* __restrict__ flag,
                                              void* __restrict__ out) {
    int bf = *flag;
    int b = blockIdx.x, l = threadIdx.x;
    float e = (tok_sum[l] + graph_sum[b * H_ + l]) * (1.0f / 1034.0f);
    float p0 = e * ld1(Wa, l * 2 + 0, bf);
    float p1 = e * ld1(Wa, l * 2 + 1, bf);
#pragma unroll
    for (int d = 32; d >= 1; d >>= 1) {
        p0 += __shfl_xor(p0, d);
        p1 += __shfl_xor(p1, d);
    }
    if (l == 0) {
        float l0 = p0 + ld1(ba, 0, bf);
        float l1 = p1 + ld1(ba, 1, bf);
        float mx = fmaxf(l0, l1);
        float e0 = expf(l0 - mx), e1 = expf(l1 - mx);
        float s = e0 + e1;
        float o0 = e0 / s, o1 = e1 / s;
        if (bf) {
            ((__hip_bfloat16*)out)[b * 2 + 0] = __float2bfloat16(o0);
            ((__hip_bfloat16*)out)[b * 2 + 1] = __float2bfloat16(o1);
        } else {
            ((float*)out)[b * 2 + 0] = o0;
            ((float*)out)[b * 2 + 1] = o1;
        }
    }
}

extern "C" void kernel_launch(void* const* d_in, const int* in_sizes, int n_in,
                              void* d_out, int out_size, void* d_ws, size_t ws_size,
                              hipStream_t stream) {
    (void)in_sizes; (void)n_in; (void)out_size; (void)ws_size;
    const void* x      = d_in[0];
    const void* tokens = d_in[1];
    const void* W1     = d_in[2];
    const void* b1     = d_in[3];
    const void* W2     = d_in[4];
    const void* b2     = d_in[5];
    const void* Wa     = d_in[6];
    const void* ba     = d_in[7];
    const int* esrc = (const int*)d_in[8];
    const int* edst = (const int*)d_in[9];

    char* w = (char*)d_ws;
    auto alloc = [&](size_t bytes) { void* p = (void*)w; w += (bytes + 255) & ~(size_t)255; return p; };
    int*      cnt       = (int*)alloc(BN * 4);
    int*      offs      = (int*)alloc(BN * 4);
    int*      maskA     = (int*)alloc(BN * 4);
    float*    inv_s     = (float*)alloc(BN * 4);
    int*      bucket    = (int*)alloc((size_t)BE * 4 + 512);            // 4 MB dense CSR
    uint32_t* y1        = (uint32_t*)alloc((size_t)(BN + 12) * 32 * 4); // node rows + pad row BN + P rows BN+1..BN+10
    uint32_t* y2        = (uint32_t*)alloc((size_t)(BN + 12) * 32 * 4);
    float*    tok_sum   = (float*)alloc(H_ * 4);
    float*    graph_sum = (float*)alloc(B_ * H_ * 4);
    short8*   Bfr       = (short8*)alloc(4 * 5 * 64 * sizeof(short8));
    short8*   Bfr2      = (short8*)alloc(2 * 4 * 64 * sizeof(short8));
    int*      dflag     = (int*)alloc(256);

    k_bucket   <<<B_, 1024, 0, stream>>>(esrc, edst, cnt, offs, bucket, graph_sum,
                                         y1 + (size_t)BN * 32, y2 + (size_t)BN * 32);
    k_prep     <<<7, 256, 0, stream>>>(W1, W2, tokens, dflag, Bfr, Bfr2);
    k_tok      <<<1, 64, 0, stream>>>(tokens, b1, b2, Bfr, Bfr2, dflag, y1, y2, tok_sum);
    k_node_mfma<<<BN / 64, 256, 0, stream>>>(x, Bfr, cnt, dflag, y1, inv_s, maskA);
    k_layer1   <<<B_ * 4, 1024, 0, stream>>>(y1, inv_s, cnt, offs, maskA, bucket, b1, Bfr2, dflag, y2);
    k_layer2   <<<B_ * 4, 1024, 0, stream>>>(y2, inv_s, cnt, offs, maskA, bucket, b2, dflag, graph_sum);
    k_final    <<<B_, 64, 0, stream>>>(graph_sum, tok_sum, Wa, ba, dflag, d_out);
}

// Round 5
// 160.024 us; speedup vs baseline: 1.7810x; 1.1510x over previous
//
#include <hip/hip_runtime.h>
#include <hip/hip_bf16.h>
#include <stdint.h>

#define B_ 64
#define N_ 1024
#define E_ 16384
#define F_ 128
#define H_ 64
#define T_ 10
#define BN (B_*N_)   // 65536
#define BE (B_*E_)   // 1048576

// sigmoid(z) >= p  <=>  z >= log(p/(1-p))
#define TH_INNER (-0.84729786f)   // logit(0.3)
#define TH_CROSS (-2.1972246f)    // logit(0.1)

typedef __attribute__((ext_vector_type(8))) short short8;  // bf16x8 MFMA frag
typedef __attribute__((ext_vector_type(4))) float f32x4;   // MFMA acc

__device__ __forceinline__ float ld1(const void* p, int i, int bf) {
    if (bf) {
        uint16_t u = ((const uint16_t*)p)[i];
        return __uint_as_float(((uint32_t)u) << 16);
    }
    return ((const float*)p)[i];
}

__device__ __forceinline__ short to_bf(float x) {
    return (short)__bfloat16_as_ushort(__float2bfloat16(x));
}

__device__ __forceinline__ uint32_t pack_bf2(float lo, float hi) {
    uint32_t l = (uint32_t)__bfloat16_as_ushort(__float2bfloat16(lo));
    uint32_t h = (uint32_t)__bfloat16_as_ushort(__float2bfloat16(hi));
    return l | (h << 16);
}

__device__ __forceinline__ float bflo(uint32_t u) { return __uint_as_float(u << 16); }
__device__ __forceinline__ float bfhi(uint32_t u) { return __uint_as_float(u & 0xffff0000u); }

// ---------------- count (256 blocks, per-quarter histograms) + fused W-prep ----------------
__global__ __launch_bounds__(1024) void k_count_prep(const int* __restrict__ dst,
                                                     int* __restrict__ cnt4,
                                                     const void* __restrict__ W1,
                                                     const void* __restrict__ W2,
                                                     const void* __restrict__ tokens,
                                                     int* __restrict__ flag,
                                                     short8* __restrict__ Bfr,
                                                     short8* __restrict__ Bfr2,
                                                     float* __restrict__ gsum,
                                                     uint32_t* __restrict__ y1pad,
                                                     uint32_t* __restrict__ y2pad) {
    __shared__ int lcnt[N_];
    int t = threadIdx.x;
    if (blockIdx.x >= 256) {                     // fused k_prep (blocks 256,257)
        uint32_t du = ((const uint32_t*)tokens)[t & 63];
        float dlo = __uint_as_float(du << 16);
        unsigned long long vote = __ballot(fabsf(dlo) <= 1.0f);
        int bf = (vote == ~0ull) ? 1 : 0;
        if (blockIdx.x == 256 && t == 0) *flag = bf;
        int f = (int)(blockIdx.x - 256) * 1024 + t;   // [0, 2048)
        if (f < 1280) {                          // Bfr: [128 x 80] = W1 | tokens^T
            int c = f / 320, rem = f % 320;
            int nt = rem / 64, lane = rem % 64;
            int q = lane >> 4, n = nt * 16 + (lane & 15);
            int k0 = c * 32 + q * 8;
            short8 v;
#pragma unroll
            for (int j = 0; j < 8; ++j) {
                int k = k0 + j;
                float x = 0.f;
                if (n < H_) x = ld1(W1, k * H_ + n, bf);
                else if (n < H_ + T_) x = ld1(tokens, (n - H_) * F_ + k, bf);
                v[j] = to_bf(x);
            }
            Bfr[f] = v;
        } else if (f < 1792) {                   // Bfr2: W2 [64 x 64]
            int f2 = f - 1280;
            int c = f2 / 256, rem = f2 % 256;
            int nt = rem / 64, lane = rem % 64;
            int q = lane >> 4, n = nt * 16 + (lane & 15);
            int k0 = c * 32 + q * 8;
            short8 v;
#pragma unroll
            for (int j = 0; j < 8; ++j) v[j] = to_bf(ld1(W2, (k0 + j) * H_ + n, bf));
            Bfr2[f2] = v;
        }
        return;
    }
    int g = blockIdx.x & 63, c = blockIdx.x >> 6;   // 4 quarter-blocks per graph
    lcnt[t] = 0;
    if (c == 0 && t < 64) gsum[g * 64 + t] = 0.f;   // zero pool row
    if (blockIdx.x == 0) {                          // zero pad rows once
        if (t < 32) y1pad[t] = 0;
        else if (t < 64) y2pad[t - 32] = 0;
    }
    __syncthreads();
#pragma unroll
    for (int it = 0; it < 4; ++it)
        atomicAdd(&lcnt[dst[g * E_ + c * 4096 + it * 1024 + t]], 1);
    __syncthreads();
    cnt4[c * BN + g * N_ + t] = lcnt[t];
}

// ---------------- scan (64 blocks): totals + quarter bases; block 64 = fused k_tok ----------------
__global__ __launch_bounds__(1024) void k_scan_tok(const int* __restrict__ cnt4,
                                                   int* __restrict__ cnt,
                                                   int* __restrict__ offs,
                                                   int* __restrict__ base4,
                                                   const void* __restrict__ tokens,
                                                   const void* __restrict__ b1,
                                                   const void* __restrict__ b2,
                                                   const short8* __restrict__ Bfr,
                                                   const short8* __restrict__ Bfr2,
                                                   const int* __restrict__ flag,
                                                   uint32_t* __restrict__ y1,
                                                   uint32_t* __restrict__ y2,
                                                   float* __restrict__ tok_sum) {
    __shared__ int wsum[16];
    __shared__ float nm[T_ * 16];
    __shared__ float ist_s[16], idt_s[16];
    __shared__ float htbuf[T_ * 64];
    __shared__ float h1s[T_ * 64];
    int t = threadIdx.x;
    if (blockIdx.x < 64) {                       // ---- scan path ----
        int g = blockIdx.x;
        int c0 = cnt4[0 * BN + g * N_ + t];
        int c1 = cnt4[1 * BN + g * N_ + t];
        int c2 = cnt4[2 * BN + g * N_ + t];
        int c3 = cnt4[3 * BN + g * N_ + t];
        int v = c0 + c1 + c2 + c3;
        int sc = v;                              // wave-level inclusive scan
#pragma unroll
        for (int d = 1; d < 64; d <<= 1) {
            int u = __shfl_up(sc, d);
            if ((t & 63) >= d) sc += u;
        }
        if ((t & 63) == 63) wsum[t >> 6] = sc;
        __syncthreads();
        if (t < 16) {
            int wsc = wsum[t];
#pragma unroll
            for (int d = 1; d < 16; d <<= 1) {
                int u = __shfl_up(wsc, d);
                if (t >= d) wsc += u;
            }
            wsum[t] = wsc;
        }
        __syncthreads();
        int base = sc - v + ((t >= 64) ? wsum[(t >> 6) - 1] : 0);
        int o = g * E_ + base;
        cnt[g * N_ + t] = v;
        offs[g * N_ + t] = o;
        base4[0 * BN + g * N_ + t] = o;
        base4[1 * BN + g * N_ + t] = o + c0;
        base4[2 * BN + g * N_ + t] = o + c0 + c1;
        base4[3 * BN + g * N_ + t] = o + c0 + c1 + c2;
        return;
    }
    // ---- tok path (block 64): wave 0 computes, all waves share barriers ----
    int bf = *flag;
    int l = t;
    bool act = (l < 64);                         // wave-uniform guard
    int m = l & 15, q = (l & 63) >> 4;
    int mrow = (m < T_) ? m : (T_ - 1);
    f32x4 accM = {};
    f32x4 acc1[4] = {};
    float istc = 0.f, idtc = 0.f;
    if (act) {
        short8 afr[4];
        if (bf) {
            const short8* ar = (const short8*)((const uint16_t*)tokens + mrow * F_);
#pragma unroll
            for (int c = 0; c < 4; ++c) afr[c] = ar[c * 4 + q];
        } else {
            const float* ar = (const float*)tokens + mrow * F_;
#pragma unroll
            for (int c = 0; c < 4; ++c)
#pragma unroll
                for (int j = 0; j < 8; ++j) afr[c][j] = to_bf(ar[c * 32 + q * 8 + j]);
        }
#pragma unroll
        for (int c = 0; c < 4; ++c) {
            accM = __builtin_amdgcn_mfma_f32_16x16x32_bf16(afr[c], Bfr[(c * 5 + 4) * 64 + l], accM, 0, 0, 0);
#pragma unroll
            for (int nt = 0; nt < 4; ++nt)
                acc1[nt] = __builtin_amdgcn_mfma_f32_16x16x32_bf16(afr[c], Bfr[(c * 5 + nt) * 64 + l], acc1[nt], 0, 0, 0);
        }
        int ccnt = 0;
#pragma unroll
        for (int r = 0; r < 4; ++r) {
            int row = q * 4 + r;
            if (row < T_ && m < T_ && accM[r] >= TH_INNER) ccnt++;
        }
        ccnt += __shfl_xor(ccnt, 16);
        ccnt += __shfl_xor(ccnt, 32);
        float deg = 1.f + (float)ccnt;
        istc = 1.f / sqrtf(deg);
        idtc = 1.f / deg;
        if (q == 0 && m < T_) { ist_s[m] = istc; idt_s[m] = idtc; }
#pragma unroll
        for (int nt = 0; nt < 4; ++nt)
#pragma unroll
            for (int r = 0; r < 4; ++r) {
                int row = q * 4 + r;
                if (row < T_) htbuf[row * 64 + nt * 16 + m] = acc1[nt][r];
            }
    }
    __syncthreads();
    if (act && m < T_) {
#pragma unroll
        for (int r = 0; r < 4; ++r) {
            int row = q * 4 + r;
            if (row < T_)
                nm[row * 16 + m] = (accM[r] >= TH_INNER) ? ist_s[row] * istc : 0.f;
        }
    }
    __syncthreads();
    if (act) {
        float htc[T_];
#pragma unroll
        for (int s = 0; s < T_; ++s) htc[s] = htbuf[s * 64 + l];
        float b1f = ld1(b1, l, bf);
#pragma unroll
        for (int tt = 0; tt < T_; ++tt) {
            float a = htc[tt] * idt_s[tt] + b1f;
#pragma unroll
            for (int s = 0; s < T_; ++s) a += nm[tt * 16 + s] * htc[s];
            a = (a >= 0.f) ? a : 0.01f * a;
            h1s[tt * 64 + l] = a;
            float v = ist_s[tt] * htc[tt];        // P1 row -> y1[BN+1+tt]
            float vh = __shfl(v, l + 1);
            if ((l & 1) == 0) y1[(size_t)(BN + 1 + tt) * 32 + (l >> 1)] = pack_bf2(v, vh);
        }
    }
    __syncthreads();
    if (act) {
        short8 a2fr[2];
#pragma unroll
        for (int c = 0; c < 2; ++c)
#pragma unroll
            for (int j = 0; j < 8; ++j) a2fr[c][j] = to_bf(h1s[mrow * 64 + c * 32 + q * 8 + j]);
        f32x4 acc2[4] = {};
#pragma unroll
        for (int nt = 0; nt < 4; ++nt)
#pragma unroll
            for (int c = 0; c < 2; ++c)
                acc2[nt] = __builtin_amdgcn_mfma_f32_16x16x32_bf16(a2fr[c], Bfr2[(c * 4 + nt) * 64 + l], acc2[nt], 0, 0, 0);
#pragma unroll
        for (int nt = 0; nt < 4; ++nt)
#pragma unroll
            for (int r = 0; r < 4; ++r) {
                int row = q * 4 + r;
                if (row < T_) htbuf[row * 64 + nt * 16 + m] = acc2[nt][r];
            }
    }
    __syncthreads();
    if (act) {
        float htc[T_];
#pragma unroll
        for (int s = 0; s < T_; ++s) htc[s] = htbuf[s * 64 + l];
        float b2f = ld1(b2, l, bf);
        float ts = 0.f;
#pragma unroll
        for (int tt = 0; tt < T_; ++tt) {
            float o = htc[tt] * idt_s[tt] + b2f;
#pragma unroll
            for (int s = 0; s < T_; ++s) o += nm[tt * 16 + s] * htc[s];
            ts += o;
            float v = ist_s[tt] * htc[tt];        // P2 row -> y2[BN+1+tt]
            float vh = __shfl(v, l + 1);
            if ((l & 1) == 0) y2[(size_t)(BN + 1 + tt) * 32 + (l >> 1)] = pack_bf2(v, vh);
        }
        tok_sum[l] = ts;
    }
}

// ---------------- scatter (256 blocks): deterministic quarter bases, LDS cursors ----------------
__global__ __launch_bounds__(1024) void k_scatter(const int* __restrict__ src,
                                                  const int* __restrict__ dst,
                                                  const int* __restrict__ base4,
                                                  int* __restrict__ bucket) {
    __shared__ int cur[N_];
    int t = threadIdx.x;
    int g = blockIdx.x & 63, c = blockIdx.x >> 6;
    cur[t] = base4[c * BN + g * N_ + t];
    __syncthreads();
#pragma unroll
    for (int it = 0; it < 4; ++it) {
        int i = g * E_ + c * 4096 + it * 1024 + t;
        int d = dst[i];
        int p = atomicAdd(&cur[d], 1);
        bucket[p] = g * N_ + src[i];
    }
}

// ---------------- node GEMM: y1 + token-mask store + inv_s ----------------
__global__ __launch_bounds__(256) void k_node_mfma(const void* __restrict__ x,
                                                   const short8* __restrict__ Bfr,
                                                   const int* __restrict__ cnt,
                                                   const int* __restrict__ flag,
                                                   uint32_t* __restrict__ y1,
                                                   float* __restrict__ inv_s,
                                                   int* __restrict__ maskA) {
    int bf = *flag;
    int tid = threadIdx.x;
    int lane = tid & 63, wv = tid >> 6;
    int g = blockIdx.x & 63, c = blockIdx.x >> 6;   // XCD swizzle
    int row0 = g * N_ + c * 64 + wv * 16;
    int m = lane & 15, q = lane >> 4;
    int row = row0 + m;
    short8 afr[4];
    if (bf) {
        const short8* ar = (const short8*)((const uint16_t*)x + (size_t)row * F_);
#pragma unroll
        for (int cc = 0; cc < 4; ++cc) afr[cc] = ar[cc * 4 + q];
    } else {
        const float* ar = (const float*)x + (size_t)row * F_;
#pragma unroll
        for (int cc = 0; cc < 4; ++cc)
#pragma unroll
            for (int j = 0; j < 8; ++j)
                afr[cc][j] = to_bf(ar[cc * 32 + q * 8 + j]);
    }
    f32x4 acc[5] = {};
#pragma unroll
    for (int nt = 0; nt < 5; ++nt)
#pragma unroll
        for (int cc = 0; cc < 4; ++cc) {
            short8 bfr = Bfr[(cc * 5 + nt) * 64 + lane];
            acc[nt] = __builtin_amdgcn_mfma_f32_16x16x32_bf16(afr[cc], bfr, acc[nt], 0, 0, 0);
        }
    unsigned long long bal[4];
#pragma unroll
    for (int r = 0; r < 4; ++r) {
        int pred = (m < T_) && (acc[4][r] >= TH_CROSS);
        bal[r] = __ballot(pred);
    }
    float isv[4];
#pragma unroll
    for (int r = 0; r < 4; ++r) {
        int node = row0 + q * 4 + r;
        int mk = (int)((bal[r] >> (q * 16)) & 0x3FF);
        int ec = cnt[node];
        int pc = __popc((unsigned)mk);
        float deg = 1.f + (float)ec + (float)pc;
        isv[r] = 1.f / sqrtf(deg);
        if (m == 0) { inv_s[node] = isv[r]; maskA[node] = mk; }
    }
#pragma unroll
    for (int r = 0; r < 4; ++r) {
        int node = row0 + q * 4 + r;
#pragma unroll
        for (int nt = 0; nt < 4; ++nt) {
            float v = acc[nt][r] * isv[r];
            float vh = __shfl(v, lane + 1);
            if ((m & 1) == 0)
                y1[(size_t)node * 32 + nt * 8 + (m >> 1)] = pack_bf2(v, vh);
        }
    }
}

#define NROWS (N_ + 12)   // graph rows + pad + 10 token P rows (+1 slack)

// stage one graph's y-slice (+token rows) into LDS, linear layout
__device__ __forceinline__ void stage_slice(uint32_t* __restrict__ ys,
                                            const uint32_t* __restrict__ yg,   // graph base
                                            const uint32_t* __restrict__ yall, // full y base
                                            int tid) {
#pragma unroll
    for (int it = 0; it < 9; ++it) {
        int idx = it * 1024 + tid;
        if (idx < NROWS * 8) {
            int r = idx >> 3, gg = idx & 7;
            const uint32_t* sp = (r < N_) ? (yg + r * 32)
                                          : (yall + (size_t)(BN + (r - N_)) * 32);
            *(uint4*)&ys[r * 32 + gg * 4] = *(const uint4*)(sp + gg * 4);
        }
    }
}

// group-mode gather: 8-lane group owns one node, reads whole rows from LDS.
// returns 8 column sums (cols wp*8 .. wp*8+7) in a[0..7]
__device__ __forceinline__ void gather_grp(const uint32_t* __restrict__ ys,
                                           const int* __restrict__ bucket,
                                           int cnt_g, int off_g, int msk_g, int self_l,
                                           int wp, float a[8]) {
#pragma unroll
    for (int j = 0; j < 8; ++j) a[j] = 0.f;
    int cm = cnt_g;                               // wave max over the 8 groups
    cm = max(cm, __shfl_xor(cm, 8));
    cm = max(cm, __shfl_xor(cm, 16));
    cm = max(cm, __shfl_xor(cm, 32));
    int nid0 = (cnt_g > 0) ? bucket[off_g] : 0;
    int nid1 = (cnt_g > 1) ? bucket[off_g + 1] : 0;
    for (int e = 0; e < cm; ++e) {
        int cur = nid0;
        nid0 = nid1;
        if (e + 2 < cnt_g) nid1 = bucket[off_g + e + 2];
        if (e < cnt_g) {
            int sl = cur & (N_ - 1);
            uint4 u = *(const uint4*)&ys[sl * 32 + wp * 4];
            a[0] += bflo(u.x); a[1] += bfhi(u.x);
            a[2] += bflo(u.y); a[3] += bfhi(u.y);
            a[4] += bflo(u.z); a[5] += bfhi(u.z);
            a[6] += bflo(u.w); a[7] += bfhi(u.w);
        }
    }
    unsigned mm = (unsigned)msk_g;                // virtual token edges from LDS rows
    while (mm) {
        int tk = __ffs(mm) - 1;
        mm &= mm - 1;
        uint4 u = *(const uint4*)&ys[(N_ + 1 + tk) * 32 + wp * 4];
        a[0] += bflo(u.x); a[1] += bfhi(u.x);
        a[2] += bflo(u.y); a[3] += bfhi(u.y);
        a[4] += bflo(u.z); a[5] += bfhi(u.z);
        a[6] += bflo(u.w); a[7] += bfhi(u.w);
    }
    {                                             // self loop
        uint4 u = *(const uint4*)&ys[self_l * 32 + wp * 4];
        a[0] += bflo(u.x); a[1] += bfhi(u.x);
        a[2] += bflo(u.y); a[3] += bfhi(u.y);
        a[4] += bflo(u.z); a[5] += bfhi(u.z);
        a[6] += bflo(u.w); a[7] += bfhi(u.w);
    }
}

// ---------------- layer1: LDS-staged group gather + fused h1@W2 -> y2 ----------------
__global__ __launch_bounds__(1024, 1) void k_layer1(const uint32_t* __restrict__ y1,
                                                    const float* __restrict__ inv_s,
                                                    const int* __restrict__ cnt,
                                                    const int* __restrict__ offs,
                                                    const int* __restrict__ maskA,
                                                    const int* __restrict__ bucket,
                                                    const void* __restrict__ b1,
                                                    const short8* __restrict__ Bfr2,
                                                    const int* __restrict__ flag,
                                                    uint32_t* __restrict__ y2) {
    __shared__ uint32_t y1s[NROWS * 32];         // 129.5 KB staged slice (linear)
    __shared__ uint32_t h1w[16][9 * 36];         // bf16-packed h1 tiles; row 8 = zeros
    int bf = *flag;
    int tid = threadIdx.x;
    int lane = tid & 63, wv = tid >> 6;
    int gi = lane >> 3, wp = lane & 7;
    int g = blockIdx.x & 63, c = blockIdx.x >> 6;   // 4 blocks/graph, same XCD
    stage_slice(y1s, y1 + (size_t)g * N_ * 32, y1, tid);
    int nbase = g * N_ + c * 256 + wv * 16;
    int ln16 = lane & 15;
    int cntv = cnt[nbase + ln16];
    int offv = offs[nbase + ln16];
    float isvv = inv_s[nbase + ln16];
    int mskv = maskA[nbase + ln16];
    float bc[8];
#pragma unroll
    for (int j = 0; j < 8; ++j) bc[j] = ld1(b1, wp * 8 + j, bf);
    if (lane < 36) h1w[wv][8 * 36 + lane] = 0;   // zero row for A-frag rows 8..15
    __syncthreads();
    int m = lane & 15, q = lane >> 4;
    int mr = (m < 8) ? m : 8;
    for (int k = 0; k < 2; ++k) {
        int ni = k * 8 + gi;
        int cnt_g = __shfl(cntv, ni);
        int off_g = __shfl(offv, ni);
        int msk_g = __shfl(mskv, ni);
        float is_g = __shfl(isvv, ni);
        float a[8];
        gather_grp(y1s, bucket, cnt_g, off_g, msk_g, c * 256 + wv * 16 + ni, wp, a);
        uint32_t pk[4];
#pragma unroll
        for (int j = 0; j < 4; ++j) {
            float h0 = a[2 * j] * is_g + bc[2 * j];
            float h1v = a[2 * j + 1] * is_g + bc[2 * j + 1];
            h0 = (h0 >= 0.f) ? h0 : 0.01f * h0;
            h1v = (h1v >= 0.f) ? h1v : 0.01f * h1v;
            pk[j] = pack_bf2(h0, h1v);
        }
#pragma unroll
        for (int j = 0; j < 4; ++j) h1w[wv][gi * 36 + wp * 4 + j] = pk[j];
        // fused GEMM on 8-node chunk (rows 8..15 read the zero row)
        short8 afr[2];
#pragma unroll
        for (int cc = 0; cc < 2; ++cc)
            afr[cc] = *(const short8*)&h1w[wv][mr * 36 + cc * 16 + q * 4];
        f32x4 acc[4] = {};
#pragma unroll
        for (int nt = 0; nt < 4; ++nt)
#pragma unroll
            for (int cc = 0; cc < 2; ++cc)
                acc[nt] = __builtin_amdgcn_mfma_f32_16x16x32_bf16(afr[cc], Bfr2[(cc * 4 + nt) * 64 + lane], acc[nt], 0, 0, 0);
#pragma unroll
        for (int r = 0; r < 4; ++r) {
            int tr = q * 4 + r;
            if (tr < 8) {
                int node = nbase + k * 8 + tr;
                float is = __shfl(isvv, k * 8 + tr);
#pragma unroll
                for (int nt = 0; nt < 4; ++nt) {
                    float v = acc[nt][r] * is;
                    float vh = __shfl(v, lane + 1);
                    if ((m & 1) == 0)
                        y2[(size_t)node * 32 + nt * 8 + (m >> 1)] = pack_bf2(v, vh);
                }
            }
        }
    }
}

// ---------------- layer2: LDS-staged group gather + pooling ----------------
__global__ __launch_bounds__(1024, 1) void k_layer2(const uint32_t* __restrict__ y2,
                                                    const float* __restrict__ inv_s,
                                                    const int* __restrict__ cnt,
                                                    const int* __restrict__ offs,
                                                    const int* __restrict__ maskA,
                                                    const int* __restrict__ bucket,
                                                    const void* __restrict__ b2,
                                                    const int* __restrict__ flag,
                                                    float* __restrict__ graph_sum) {
    __shared__ uint32_t y2s[NROWS * 32];         // 129.5 KB staged slice (linear)
    __shared__ float pool[16][64];
    int bf = *flag;
    int tid = threadIdx.x;
    int lane = tid & 63, wv = tid >> 6;
    int gi = lane >> 3, wp = lane & 7;
    int g = blockIdx.x & 63, c = blockIdx.x >> 6;
    stage_slice(y2s, y2 + (size_t)g * N_ * 32, y2, tid);
    int nbase = g * N_ + c * 256 + wv * 16;
    int ln16 = lane & 15;
    int cntv = cnt[nbase + ln16];
    int offv = offs[nbase + ln16];
    float isvv = inv_s[nbase + ln16];
    int mskv = maskA[nbase + ln16];
    float bc[8];
#pragma unroll
    for (int j = 0; j < 8; ++j) bc[j] = ld1(b2, wp * 8 + j, bf);
    __syncthreads();
    float p[8];
#pragma unroll
    for (int j = 0; j < 8; ++j) p[j] = 0.f;
    for (int k = 0; k < 2; ++k) {
        int ni = k * 8 + gi;
        int cnt_g = __shfl(cntv, ni);
        int off_g = __shfl(offv, ni);
        int msk_g = __shfl(mskv, ni);
        float is_g = __shfl(isvv, ni);
        float a[8];
        gather_grp(y2s, bucket, cnt_g, off_g, msk_g, c * 256 + wv * 16 + ni, wp, a);
#pragma unroll
        for (int j = 0; j < 8; ++j) p[j] += a[j] * is_g + bc[j];
    }
#pragma unroll
    for (int j = 0; j < 8; ++j) {                // reduce across the 8 groups
        p[j] += __shfl_xor(p[j], 8);
        p[j] += __shfl_xor(p[j], 16);
        p[j] += __shfl_xor(p[j], 32);
    }
    if (gi == 0) {
#pragma unroll
        for (int j = 0; j < 8; ++j) pool[wv][wp * 8 + j] = p[j];
    }
    __syncthreads();
    if (tid < 64) {
        float s = 0.f;
#pragma unroll
        for (int w2 = 0; w2 < 16; ++w2) s += pool[w2][tid];
        atomicAdd(&graph_sum[g * H_ + tid], s);
    }
}

// ---------------- pooled emb -> answering head -> softmax ----------------
__global__ __launch_bounds__(64) void k_final(const float* __restrict__ graph_sum,
                                              const float* __restrict__ tok_sum,
                                              const void* __restrict__ Wa,
                                              const void* __restrict__ ba,
                                              const int* __restrict__ flag,
                                              void* __restrict__ out) {
    int bf = *flag;
    int b = blockIdx.x, l = threadIdx.x;
    float e = (tok_sum[l] + graph_sum[b * H_ + l]) * (1.0f / 1034.0f);
    float p0 = e * ld1(Wa, l * 2 + 0, bf);
    float p1 = e * ld1(Wa, l * 2 + 1, bf);
#pragma unroll
    for (int d = 32; d >= 1; d >>= 1) {
        p0 += __shfl_xor(p0, d);
        p1 += __shfl_xor(p1, d);
    }
    if (l == 0) {
        float l0 = p0 + ld1(ba, 0, bf);
        float l1 = p1 + ld1(ba, 1, bf);
        float mx = fmaxf(l0, l1);
        float e0 = expf(l0 - mx), e1 = expf(l1 - mx);
        float s = e0 + e1;
        float o0 = e0 / s, o1 = e1 / s;
        if (bf) {
            ((__hip_bfloat16*)out)[b * 2 + 0] = __float2bfloat16(o0);
            ((__hip_bfloat16*)out)[b * 2 + 1] = __float2bfloat16(o1);
        } else {
            ((float*)out)[b * 2 + 0] = o0;
            ((float*)out)[b * 2 + 1] = o1;
        }
    }
}

extern "C" void kernel_launch(void* const* d_in, const int* in_sizes, int n_in,
                              void* d_out, int out_size, void* d_ws, size_t ws_size,
                              hipStream_t stream) {
    (void)in_sizes; (void)n_in; (void)out_size; (void)ws_size;
    const void* x      = d_in[0];
    const void* tokens = d_in[1];
    const void* W1     = d_in[2];
    const void* b1     = d_in[3];
    const void* W2     = d_in[4];
    const void* b2     = d_in[5];
    const void* Wa     = d_in[6];
    const void* ba     = d_in[7];
    const int* esrc = (const int*)d_in[8];
    const int* edst = (const int*)d_in[9];

    char* w = (char*)d_ws;
    auto alloc = [&](size_t bytes) { void* p = (void*)w; w += (bytes + 255) & ~(size_t)255; return p; };
    int*      cnt       = (int*)alloc(BN * 4);
    int*      offs      = (int*)alloc(BN * 4);
    int*      maskA     = (int*)alloc(BN * 4);
    float*    inv_s     = (float*)alloc(BN * 4);
    int*      cnt4      = (int*)alloc((size_t)4 * BN * 4);
    int*      base4     = (int*)alloc((size_t)4 * BN * 4);
    int*      bucket    = (int*)alloc((size_t)BE * 4 + 512);            // 4 MB dense CSR
    uint32_t* y1        = (uint32_t*)alloc((size_t)(BN + 12) * 32 * 4); // node rows + pad + P rows
    uint32_t* y2        = (uint32_t*)alloc((size_t)(BN + 12) * 32 * 4);
    float*    tok_sum   = (float*)alloc(H_ * 4);
    float*    graph_sum = (float*)alloc(B_ * H_ * 4);
    short8*   Bfr       = (short8*)alloc(4 * 5 * 64 * sizeof(short8));
    short8*   Bfr2      = (short8*)alloc(2 * 4 * 64 * sizeof(short8));
    int*      dflag     = (int*)alloc(256);

    k_count_prep<<<258, 1024, 0, stream>>>(edst, cnt4, W1, W2, tokens, dflag, Bfr, Bfr2,
                                           graph_sum, y1 + (size_t)BN * 32, y2 + (size_t)BN * 32);
    k_scan_tok  <<<65, 1024, 0, stream>>>(cnt4, cnt, offs, base4, tokens, b1, b2,
                                          Bfr, Bfr2, dflag, y1, y2, tok_sum);
    k_scatter   <<<256, 1024, 0, stream>>>(esrc, edst, base4, bucket);
    k_node_mfma <<<BN / 64, 256, 0, stream>>>(x, Bfr, cnt, dflag, y1, inv_s, maskA);
    k_layer1    <<<B_ * 4, 1024, 0, stream>>>(y1, inv_s, cnt, offs, maskA, bucket, b1, Bfr2, dflag, y2);
    k_layer2    <<<B_ * 4, 1024, 0, stream>>>(y2, inv_s, cnt, offs, maskA, bucket, b2, dflag, graph_sum);
    k_final     <<<B_, 64, 0, stream>>>(graph_sum, tok_sum, Wa, ba, dflag, d_out);
}